// Round 16
// baseline (909.868 us; speedup 1.0000x reference)
//
#include <hip/hip_runtime.h>
#include <hip/hip_bf16.h>

#define BB 2
#define SS 2048
#define EE 1024
#define HH 16
#define DD 64
#define FF 4096
#define VV 32000
#define LL 2
#define BS (BB*SS)

#define NEG_HUGE (-3.402823466e+38f)
#define SC_LOG2 (0.18033688011112042f)   // 0.125 * log2(e)

typedef __attribute__((ext_vector_type(4)))  float  f32x4;
typedef __attribute__((ext_vector_type(16))) float  f32x16;
typedef __attribute__((ext_vector_type(8)))  __bf16 bf16x8;
typedef __attribute__((ext_vector_type(4)))  __bf16 bf16x4;

__device__ inline bf16x8 to_bf8(float4 a, float4 b) {
  bf16x8 r;
  r[0] = (__bf16)a.x; r[1] = (__bf16)a.y; r[2] = (__bf16)a.z; r[3] = (__bf16)a.w;
  r[4] = (__bf16)b.x; r[5] = (__bf16)b.y; r[6] = (__bf16)b.z; r[7] = (__bf16)b.w;
  return r;
}

typedef const unsigned int __attribute__((address_space(1)))* gptr_t;
typedef unsigned int __attribute__((address_space(3)))* lptr_t;
__device__ inline void gload16(const void* g, void* l) {
  __builtin_amdgcn_global_load_lds((gptr_t)g, (lptr_t)l, 16, 0, 0);
}

// ---------------------------------------------------------------------------
// last_start via parallel max-scan (1 block per batch row).
// ---------------------------------------------------------------------------
__global__ __launch_bounds__(1024) void lastart_scan(
    const int* __restrict__ tokens, int* __restrict__ ls) {
  __shared__ int buf[SS];
  const int b = blockIdx.x, t = threadIdx.x;
#pragma unroll
  for (int j = 0; j < 2; ++j) {
    int i = t + j * 1024;
    buf[i] = (i > 0 && tokens[b*SS + i] == 1) ? i : 0;
  }
  __syncthreads();
  for (int off = 1; off < SS; off <<= 1) {
    int i0 = t, i1 = t + 1024;
    int v0 = (i0 >= off) ? max(buf[i0], buf[i0 - off]) : buf[i0];
    int v1 = (i1 >= off) ? max(buf[i1], buf[i1 - off]) : buf[i1];
    __syncthreads();
    buf[i0] = v0; buf[i1] = v1;
    __syncthreads();
  }
#pragma unroll
  for (int j = 0; j < 2; ++j) {
    int i = t + j * 1024;
    ls[b*SS + i] = buf[i];
  }
}

__global__ __launch_bounds__(256) void embed_kernel(
    const int* __restrict__ tokens, const int* __restrict__ ls,
    const float* __restrict__ we, const float* __restrict__ pe,
    float* __restrict__ x, __bf16* __restrict__ xb) {
  int row = blockIdx.x;
  int s = row & (SS - 1);
  int tok = tokens[row];
  int rp = s - ls[row];
  const float4* w4 = (const float4*)(we + (size_t)tok * EE);
  const float4* p4 = (const float4*)(pe + (size_t)rp * EE);
  float4 a = w4[threadIdx.x];
  float4 b = p4[threadIdx.x];
  float4 o; o.x = a.x + b.x; o.y = a.y + b.y; o.z = a.z + b.z; o.w = a.w + b.w;
  ((float4*)(x + (size_t)row * EE))[threadIdx.x] = o;
  bf16x4 ob4;
  ob4[0] = (__bf16)o.x; ob4[1] = (__bf16)o.y; ob4[2] = (__bf16)o.z; ob4[3] = (__bf16)o.w;
  *(bf16x4*)(xb + (size_t)row * EE + threadIdx.x * 4) = ob4;
}

// ---------------------------------------------------------------------------
__global__ __launch_bounds__(256) void cvt_bf16_kernel(
    const float* __restrict__ src, __bf16* __restrict__ dst, int n) {
  int i = (blockIdx.x * 256 + threadIdx.x) * 8;
  if (i + 8 > n) return;
  float4 a = *(const float4*)(src + i);
  float4 b = *(const float4*)(src + i + 4);
  *(bf16x8*)(dst + i) = to_bf8(a, b);
}

// ---------------------------------------------------------------------------
// split-K reduce: out = bf16(p0 + p1 + bias[col]).
// ---------------------------------------------------------------------------
__global__ __launch_bounds__(256) void splitk_reduce_bias(
    const float* __restrict__ p0, const float* __restrict__ p1,
    const float* __restrict__ bias, __bf16* __restrict__ out, int N) {
  const int i = (blockIdx.x * 256 + threadIdx.x) * 8;
  float4 a0 = *(const float4*)(p0 + i);
  float4 a1 = *(const float4*)(p0 + i + 4);
  float4 b0 = *(const float4*)(p1 + i);
  float4 b1 = *(const float4*)(p1 + i + 4);
  const float* bp = bias + (i & (N - 1));    // N power of two
  bf16x8 o;
  o[0] = (__bf16)(a0.x + b0.x + bp[0]);
  o[1] = (__bf16)(a0.y + b0.y + bp[1]);
  o[2] = (__bf16)(a0.z + b0.z + bp[2]);
  o[3] = (__bf16)(a0.w + b0.w + bp[3]);
  o[4] = (__bf16)(a1.x + b1.x + bp[4]);
  o[5] = (__bf16)(a1.y + b1.y + bp[5]);
  o[6] = (__bf16)(a1.z + b1.z + bp[6]);
  o[7] = (__bf16)(a1.w + b1.w + bp[7]);
  *(bf16x8*)(out + i) = o;
}

// ---------------------------------------------------------------------------
// Persistent 8-phase 256x256 GEMM (r9-verified schedule).
// ---------------------------------------------------------------------------
__device__ inline void stage_half8(const __bf16* __restrict__ base,
                                   __bf16* region, int K, int kofs,
                                   int col8, int srow, int sdst) {
#pragma unroll
  for (int p = 0; p < 2; ++p)
    gload16(base + (size_t)(p * 128 + srow) * K + kofs + col8,
            region + p * 4096 + sdst);
}

template<int NMT, bool BIAS, bool RELU, bool OUTBF16>
__global__ __launch_bounds__(512, 2) void gemm_8ph(
    const __bf16* __restrict__ A, const __bf16* __restrict__ W,
    const float* __restrict__ bias, void* __restrict__ Cv,
    int N, int K, int nmg) {
  __shared__ __bf16 lds[8][8192];              // [c*4 + ab*2 + kh][256*32]
  const int t = threadIdx.x, l = t & 63, w = t >> 6;
  const int nwg = gridDim.x, orig = blockIdx.x;
  const int q = nwg >> 3, r = nwg & 7, xcd = orig & 7, pos = orig >> 3;
  const int wgid = (xcd < r ? xcd*(q+1) : r*(q+1) + (xcd-r)*q) + pos;
  const int mgrp = wgid % nmg, n0 = (wgid / nmg) * 256;
  const int wm = w >> 2, wn = w & 3;
  const int fr = l & 15, c8 = l >> 4;
  const int swz = (c8 ^ ((fr >> 1) & 3)) * 8;
  const int roA = (wm*128 + fr) * 32 + swz;
  const int roB = (wn*64  + fr) * 32 + swz;
  const int col8 = ((t & 3) ^ ((t >> 3) & 3)) * 8;
  const int srow = t >> 2;
  const int sdst = (t >> 6) * 512;

  const __bf16* Wb = W + (size_t)n0 * K;
  const int ng = NMT * 16;

  float bv[4];
#pragma unroll
  for (int j = 0; j < 4; ++j) bv[j] = BIAS ? bias[n0 + wn*64 + fr + j*16] : 0.0f;

  f32x4 acc[8][4] = {};

#define ABASE(g2) (A + (size_t)(mgrp*NMT + ((g2) >> 4)) * 256 * K)
#define KOFS(g2)  (((g2) & 15) * 64)

  stage_half8(ABASE(0), &lds[0][0], K, 0,  col8, srow, sdst);
  stage_half8(Wb,       &lds[2][0], K, 0,  col8, srow, sdst);
  stage_half8(ABASE(0), &lds[1][0], K, 32, col8, srow, sdst);
  stage_half8(Wb,       &lds[3][0], K, 32, col8, srow, sdst);
  stage_half8(ABASE(1), &lds[4][0], K, 64, col8, srow, sdst);
  stage_half8(Wb,       &lds[6][0], K, 64, col8, srow, sdst);
  asm volatile("s_waitcnt vmcnt(4)" ::: "memory");
  __builtin_amdgcn_s_barrier();

  for (int g = 0; g < ng; ++g) {
    const int c = g & 1;
    const int rA = c*4, rB = c*4 + 2;
    bf16x8 afr0[4], afr1[4], bfr[4];
    // ---- P1: kh0 — read B, A-lo, A-hi (hi completes under MFMA) ----
#pragma unroll
    for (int j = 0; j < 4; ++j) bfr[j]  = *(const bf16x8*)&lds[rB][roB + j*512];
#pragma unroll
    for (int i = 0; i < 4; ++i) afr0[i] = *(const bf16x8*)&lds[rA][roA + i*512];
#pragma unroll
    for (int i = 0; i < 4; ++i) afr1[i] = *(const bf16x8*)&lds[rA][roA + (i+4)*512];
    if (g + 1 < ng)
      stage_half8(ABASE(g+1), &lds[(c^1)*4 + 1][0], K, KOFS(g+1) + 32, col8, srow, sdst);
    __builtin_amdgcn_s_barrier();
    __builtin_amdgcn_s_setprio(1);
#pragma unroll
    for (int i = 0; i < 4; ++i)
#pragma unroll
      for (int j = 0; j < 4; ++j)
        acc[i][j] = __builtin_amdgcn_mfma_f32_16x16x32_bf16(afr0[i], bfr[j], acc[i][j], 0, 0, 0);
    __builtin_amdgcn_s_setprio(0);
    __builtin_amdgcn_s_barrier();
    // ---- P2: kh0 hi — pure MFMA ----
    if (g + 1 < ng)
      stage_half8(Wb, &lds[(c^1)*4 + 3][0], K, KOFS(g+1) + 32, col8, srow, sdst);
    __builtin_amdgcn_s_barrier();
    __builtin_amdgcn_s_setprio(1);
#pragma unroll
    for (int i = 0; i < 4; ++i)
#pragma unroll
      for (int j = 0; j < 4; ++j)
        acc[i+4][j] = __builtin_amdgcn_mfma_f32_16x16x32_bf16(afr1[i], bfr[j], acc[i+4][j], 0, 0, 0);
    __builtin_amdgcn_s_setprio(0);
    if (g < ng - 1) { asm volatile("s_waitcnt vmcnt(8)" ::: "memory"); }
    else            { asm volatile("s_waitcnt vmcnt(0)" ::: "memory"); }
    __builtin_amdgcn_s_barrier();
    // ---- P3: kh1 — read B, A-lo, A-hi ----
#pragma unroll
    for (int j = 0; j < 4; ++j) bfr[j]  = *(const bf16x8*)&lds[rB + 1][roB + j*512];
#pragma unroll
    for (int i = 0; i < 4; ++i) afr0[i] = *(const bf16x8*)&lds[rA + 1][roA + i*512];
#pragma unroll
    for (int i = 0; i < 4; ++i) afr1[i] = *(const bf16x8*)&lds[rA + 1][roA + (i+4)*512];
    if (g + 2 < ng)
      stage_half8(ABASE(g+2), &lds[c*4][0], K, KOFS(g+2), col8, srow, sdst);
    __builtin_amdgcn_s_barrier();
    __builtin_amdgcn_s_setprio(1);
#pragma unroll
    for (int i = 0; i < 4; ++i)
#pragma unroll
      for (int j = 0; j < 4; ++j)
        acc[i][j] = __builtin_amdgcn_mfma_f32_16x16x32_bf16(afr0[i], bfr[j], acc[i][j], 0, 0, 0);
    __builtin_amdgcn_s_setprio(0);
    __builtin_amdgcn_s_barrier();
    // ---- P4: kh1 hi — pure MFMA ----
    if (g + 2 < ng)
      stage_half8(Wb, &lds[c*4 + 2][0], K, KOFS(g+2), col8, srow, sdst);
    __builtin_amdgcn_s_barrier();
    __builtin_amdgcn_s_setprio(1);
#pragma unroll
    for (int i = 0; i < 4; ++i)
#pragma unroll
      for (int j = 0; j < 4; ++j)
        acc[i+4][j] = __builtin_amdgcn_mfma_f32_16x16x32_bf16(afr1[i], bfr[j], acc[i+4][j], 0, 0, 0);
    __builtin_amdgcn_s_setprio(0);
    if (g < ng - 2)       { asm volatile("s_waitcnt vmcnt(8)" ::: "memory"); }
    else if (g == ng - 2) { asm volatile("s_waitcnt vmcnt(4)" ::: "memory"); }
    __builtin_amdgcn_s_barrier();
    // ---- per-tile epilogue (regs only) ----
    if ((g & 15) == 15) {
      const int orow = (mgrp*NMT + (g >> 4)) * 256 + wm*128 + c8 * 4;
      const int ocol = n0 + wn*64 + fr;
#pragma unroll
      for (int i = 0; i < 8; ++i)
#pragma unroll
        for (int j = 0; j < 4; ++j) {
#pragma unroll
          for (int rr = 0; rr < 4; ++rr) {
            float v = acc[i][j][rr] + bv[j];
            if (RELU) v = fmaxf(v, 0.0f);
            if (OUTBF16)
              ((__bf16*)Cv)[(size_t)(orow + i*16 + rr) * N + ocol + j*16] = (__bf16)v;
            else
              ((float*)Cv)[(size_t)(orow + i*16 + rr) * N + ocol + j*16] = v;
          }
          acc[i][j] = (f32x4){};
        }
    }
  }
#undef ABASE
#undef KOFS
}

// ---------------------------------------------------------------------------
// Deep-prefetch 128x128 GEMM (r6-verified; wo shape).
// ---------------------------------------------------------------------------
template<int T, int BM>
__device__ inline void stage2(const __bf16* __restrict__ Ab,
                              const __bf16* __restrict__ Wb,
                              __bf16* la, __bf16* lb, int K, int k0, int t) {
  const int col8 = (t & 3) ^ ((t >> 3) & 3);
  const int cofs = k0 + col8 * 8;
  const int wbase = (t >> 6) * 512;
#pragma unroll
  for (int p = 0; p < (BM * 32) / (T * 8); ++p) {
    const int row = p * (T >> 2) + (t >> 2);
    gload16(Ab + (size_t)row * K + cofs, la + p * T * 8 + wbase);
    gload16(Wb + (size_t)row * K + cofs, lb + p * T * 8 + wbase);
  }
}

template<int RW, int WM, int WN, bool BIAS, bool RELU, bool OUTBF16>
__global__ __launch_bounds__(WM*WN*64, 2) void gemm_deep(
    const __bf16* __restrict__ A, const __bf16* __restrict__ W,
    const float* __restrict__ bias, void* __restrict__ Cv,
    int N, int K, int nbx) {
  constexpr int T  = WM * WN * 64;
  constexpr int BM = WM * RW * 16;
  __shared__ __bf16 lds[4][2][BM * 32];
  const int t = threadIdx.x, l = t & 63, w = t >> 6;
  const int nwg = gridDim.x, orig = blockIdx.x;
  const int q = nwg >> 3, r = nwg & 7, xcd = orig & 7, pos = orig >> 3;
  const int wgid = (xcd < r ? xcd*(q+1) : r*(q+1) + (xcd-r)*q) + pos;
  const int m0 = (wgid % nbx) * BM, n0 = (wgid / nbx) * BM;
  const int wm = w / WN, wn = w % WN;
  const int fr = l & 15, c8 = l >> 4;
  const int slot = (c8 ^ ((fr >> 1) & 3)) * 8;

  const __bf16* Abase = A + (size_t)m0 * K;
  const __bf16* Wbase = W + (size_t)n0 * K;

  f32x4 acc[RW][4] = {};

  const int nk = K >> 5;
  stage2<T,BM>(Abase, Wbase, &lds[0][0][0], &lds[0][1][0], K, 0,  t);
  stage2<T,BM>(Abase, Wbase, &lds[1][0][0], &lds[1][1][0], K, 32, t);
  stage2<T,BM>(Abase, Wbase, &lds[2][0][0], &lds[2][1][0], K, 64, t);

  for (int kt = 0; kt < nk; ++kt) {
    const int cur = kt & 3;
    if (kt + 3 < nk) {
      const int nb = (kt + 3) & 3;
      stage2<T,BM>(Abase, Wbase, &lds[nb][0][0], &lds[nb][1][0], K, (kt+3)*32, t);
      asm volatile("s_waitcnt vmcnt(8)" ::: "memory");
    } else if (kt + 2 < nk) {
      asm volatile("s_waitcnt vmcnt(8)" ::: "memory");
    } else if (kt + 1 < nk) {
      asm volatile("s_waitcnt vmcnt(4)" ::: "memory");
    } else {
      asm volatile("s_waitcnt vmcnt(0)" ::: "memory");
    }
    __builtin_amdgcn_s_barrier();
    __builtin_amdgcn_sched_barrier(0);
    const __bf16* La = &lds[cur][0][0];
    const __bf16* Lb = &lds[cur][1][0];
    bf16x8 bfr[4];
#pragma unroll
    for (int j = 0; j < 4; ++j)
      bfr[j] = *(const bf16x8*)&Lb[(wn*64 + j*16 + fr) * 32 + slot];
    __builtin_amdgcn_s_setprio(1);
#pragma unroll
    for (int i = 0; i < RW; ++i) {
      bf16x8 af = *(const bf16x8*)&La[(wm*(RW*16) + i*16 + fr) * 32 + slot];
#pragma unroll
      for (int j = 0; j < 4; ++j)
        acc[i][j] = __builtin_amdgcn_mfma_f32_16x16x32_bf16(af, bfr[j], acc[i][j], 0, 0, 0);
    }
    __builtin_amdgcn_s_setprio(0);
    __builtin_amdgcn_sched_barrier(0);
    __builtin_amdgcn_s_barrier();
    __builtin_amdgcn_sched_barrier(0);
  }

  const int orow = m0 + wm*(RW*16) + c8 * 4;
  const int ocol = n0 + wn*64 + fr;
#pragma unroll
  for (int i = 0; i < RW; ++i)
#pragma unroll
    for (int j = 0; j < 4; ++j) {
      const int col = ocol + j * 16;
      const float bv = BIAS ? bias[col] : 0.0f;
#pragma unroll
      for (int rr = 0; rr < 4; ++rr) {
        float v = acc[i][j][rr] + bv;
        if (RELU) v = fmaxf(v, 0.0f);
        if (OUTBF16)
          ((__bf16*)Cv)[(size_t)(orow + i*16 + rr) * N + col] = (__bf16)v;
        else
          ((float*)Cv)[(size_t)(orow + i*16 + rr) * N + col] = v;
      }
    }
}

// ---------------------------------------------------------------------------
// Split-K deep-prefetch 128x128 GEMM (r16): same r6-verified ledger; grid =
// 2 x tiles (slice = wgid&1 works K-range [slice*Klen, slice*Klen+Klen));
// fp32 partials to P + slice*M*N. Fills both blocks/CU slots for down's
// 256-tile shape (two 64-iter K-loops per CU overlap each other's stalls).
// ---------------------------------------------------------------------------
template<int RW, int WM, int WN>
__global__ __launch_bounds__(WM*WN*64, 2) void gemm_deep_sk(
    const __bf16* __restrict__ A, const __bf16* __restrict__ W,
    float* __restrict__ P, int N, int Kfull, int Klen, int nbx, int M) {
  constexpr int T  = WM * WN * 64;
  constexpr int BM = WM * RW * 16;
  __shared__ __bf16 lds[4][2][BM * 32];
  const int t = threadIdx.x, l = t & 63, w = t >> 6;
  const int nwg = gridDim.x, orig = blockIdx.x;
  const int q = nwg >> 3, r = nwg & 7, xcd = orig & 7, pos = orig >> 3;
  const int wgid = (xcd < r ? xcd*(q+1) : r*(q+1) + (xcd-r)*q) + pos;
  const int slice = wgid & 1, tile = wgid >> 1;
  const int m0 = (tile % nbx) * BM, n0 = (tile / nbx) * BM;
  const int wm = w / WN, wn = w % WN;
  const int fr = l & 15, c8 = l >> 4;
  const int slot = (c8 ^ ((fr >> 1) & 3)) * 8;

  const __bf16* Abase = A + (size_t)m0 * Kfull + slice * Klen;
  const __bf16* Wbase = W + (size_t)n0 * Kfull + slice * Klen;
  float* Pb = P + (size_t)slice * M * N;

  f32x4 acc[RW][4] = {};

  const int nk = Klen >> 5;
  stage2<T,BM>(Abase, Wbase, &lds[0][0][0], &lds[0][1][0], Kfull, 0,  t);
  stage2<T,BM>(Abase, Wbase, &lds[1][0][0], &lds[1][1][0], Kfull, 32, t);
  stage2<T,BM>(Abase, Wbase, &lds[2][0][0], &lds[2][1][0], Kfull, 64, t);

  for (int kt = 0; kt < nk; ++kt) {
    const int cur = kt & 3;
    if (kt + 3 < nk) {
      const int nb = (kt + 3) & 3;
      stage2<T,BM>(Abase, Wbase, &lds[nb][0][0], &lds[nb][1][0], Kfull, (kt+3)*32, t);
      asm volatile("s_waitcnt vmcnt(8)" ::: "memory");
    } else if (kt + 2 < nk) {
      asm volatile("s_waitcnt vmcnt(8)" ::: "memory");
    } else if (kt + 1 < nk) {
      asm volatile("s_waitcnt vmcnt(4)" ::: "memory");
    } else {
      asm volatile("s_waitcnt vmcnt(0)" ::: "memory");
    }
    __builtin_amdgcn_s_barrier();
    __builtin_amdgcn_sched_barrier(0);
    const __bf16* La = &lds[cur][0][0];
    const __bf16* Lb = &lds[cur][1][0];
    bf16x8 bfr[4];
#pragma unroll
    for (int j = 0; j < 4; ++j)
      bfr[j] = *(const bf16x8*)&Lb[(wn*64 + j*16 + fr) * 32 + slot];
    __builtin_amdgcn_s_setprio(1);
#pragma unroll
    for (int i = 0; i < RW; ++i) {
      bf16x8 af = *(const bf16x8*)&La[(wm*(RW*16) + i*16 + fr) * 32 + slot];
#pragma unroll
      for (int j = 0; j < 4; ++j)
        acc[i][j] = __builtin_amdgcn_mfma_f32_16x16x32_bf16(af, bfr[j], acc[i][j], 0, 0, 0);
    }
    __builtin_amdgcn_s_setprio(0);
    __builtin_amdgcn_sched_barrier(0);
    __builtin_amdgcn_s_barrier();
    __builtin_amdgcn_sched_barrier(0);
  }

  const int orow = m0 + wm*(RW*16) + c8 * 4;
  const int ocol = n0 + wn*64 + fr;
#pragma unroll
  for (int i = 0; i < RW; ++i)
#pragma unroll
    for (int j = 0; j < 4; ++j)
#pragma unroll
      for (int rr = 0; rr < 4; ++rr)
        Pb[(size_t)(orow + i*16 + rr) * N + ocol + j*16] = acc[i][j][rr];
}

// ---------------------------------------------------------------------------
// 128x128 2-phase GEMM (fallback unembed only: fp32 W reg-staged).
// ---------------------------------------------------------------------------
template<bool WBF16, bool BIAS, bool RELU, bool OUTBF16>
__global__ __launch_bounds__(256) void gemm_fast(
    const __bf16* __restrict__ A, const void* __restrict__ Wv,
    const float* __restrict__ bias, void* __restrict__ Cv, int N, int K) {
  __shared__ __bf16 As[128][32];
  __shared__ __bf16 Bs[128][32];
  const int t = threadIdx.x;
  const int m0 = blockIdx.x * 128, n0 = blockIdx.y * 128;
  const int l = t & 63, w = t >> 6;
  const int wm = (w >> 1) * 64, wn = (w & 1) * 64;
  const int fr = l & 15, fk = (l >> 4) * 8;
  const int crow = l >> 2, ccol = (l & 3) * 8;
  const int wrow = t >> 1, wcol = (t & 1) * 16;

  const __bf16* Wb = (const __bf16*)Wv;
  const float*  Wf = (const float*)Wv;

  f32x4 acc[4][4] = {};

  for (int k0 = 0; k0 < K; k0 += 32) {
    float4 wf0, wf1, wf2, wf3;
    if (!WBF16) {
      const float* wp = Wf + (size_t)(n0 + wrow) * K + k0 + wcol;
      wf0 = *(const float4*)(wp);
      wf1 = *(const float4*)(wp + 4);
      wf2 = *(const float4*)(wp + 8);
      wf3 = *(const float4*)(wp + 12);
    }
    __syncthreads();
#pragma unroll
    for (int i = 0; i < 2; ++i) {
      const int c = 2 * w + i;
      gload16(A + (size_t)(m0 + c*16 + crow) * K + k0 + ccol, (__bf16*)As + c*512);
      if (WBF16)
        gload16(Wb + (size_t)(n0 + c*16 + crow) * K + k0 + ccol, (__bf16*)Bs + c*512);
    }
    if (!WBF16) {
      *(bf16x8*)&Bs[wrow][wcol]     = to_bf8(wf0, wf1);
      *(bf16x8*)&Bs[wrow][wcol + 8] = to_bf8(wf2, wf3);
    }
    __syncthreads();
    bf16x8 af[4], bf[4];
#pragma unroll
    for (int i = 0; i < 4; ++i) af[i] = *(const bf16x8*)&As[wm + i*16 + fr][fk];
#pragma unroll
    for (int j = 0; j < 4; ++j) bf[j] = *(const bf16x8*)&Bs[wn + j*16 + fr][fk];
#pragma unroll
    for (int i = 0; i < 4; ++i)
#pragma unroll
      for (int j = 0; j < 4; ++j)
        acc[i][j] = __builtin_amdgcn_mfma_f32_16x16x32_bf16(af[i], bf[j], acc[i][j], 0, 0, 0);
  }

  const int orow = m0 + wm + (l >> 4) * 4;
  const int ocol = n0 + wn + fr;
#pragma unroll
  for (int i = 0; i < 4; ++i)
#pragma unroll
    for (int j = 0; j < 4; ++j) {
      const int col = ocol + j * 16;
      const float bv = BIAS ? bias[col] : 0.0f;
#pragma unroll
      for (int r = 0; r < 4; ++r) {
        float v = acc[i][j][r] + bv;
        if (RELU) v = fmaxf(v, 0.0f);
        if (OUTBF16)
          ((__bf16*)Cv)[(size_t)(orow + i*16 + r) * N + col] = (__bf16)v;
        else
          ((float*)Cv)[(size_t)(orow + i*16 + r) * N + col] = v;
      }
    }
}

// ---------------------------------------------------------------------------
// x = LN(y + x) * s + b ; y is bf16. Also emit bf16 copy xb.
// ---------------------------------------------------------------------------
__global__ __launch_bounds__(256) void ln_res_kernel(
    const __bf16* __restrict__ y, float* __restrict__ x, __bf16* __restrict__ xb,
    const float* __restrict__ sc, const float* __restrict__ bs) {
  __shared__ float red[8];
  int row = blockIdx.x, t = threadIdx.x;
  bf16x4 a4 = *(const bf16x4*)(y + (size_t)row * EE + t * 4);
  float4* x4 = (float4*)(x + (size_t)row * EE);
  float4 c = x4[t];
  float v0 = (float)a4[0] + c.x, v1 = (float)a4[1] + c.y;
  float v2 = (float)a4[2] + c.z, v3 = (float)a4[3] + c.w;
  float s = v0 + v1 + v2 + v3;
  float q = v0*v0 + v1*v1 + v2*v2 + v3*v3;
#pragma unroll
  for (int off = 32; off; off >>= 1) {
    s += __shfl_xor(s, off);
    q += __shfl_xor(q, off);
  }
  int w = t >> 6;
  if ((t & 63) == 0) { red[w] = s; red[4 + w] = q; }
  __syncthreads();
  s = red[0] + red[1] + red[2] + red[3];
  q = red[4] + red[5] + red[6] + red[7];
  float mean = s * (1.0f / EE);
  float var  = q * (1.0f / EE) - mean * mean;
  float r = 1.0f / sqrtf(var + 1e-6f);
  float4 ss = ((const float4*)sc)[t];
  float4 bb = ((const float4*)bs)[t];
  float4 o;
  o.x = (v0 - mean) * r * ss.x + bb.x;
  o.y = (v1 - mean) * r * ss.y + bb.y;
  o.z = (v2 - mean) * r * ss.z + bb.z;
  o.w = (v3 - mean) * r * ss.w + bb.w;
  x4[t] = o;
  bf16x4 ob4;
  ob4[0] = (__bf16)o.x; ob4[1] = (__bf16)o.y; ob4[2] = (__bf16)o.z; ob4[3] = (__bf16)o.w;
  *(bf16x4*)(xb + (size_t)row * EE + t * 4) = ob4;
}

// ---------------------------------------------------------------------------
// MFMA flash attention (r8/r11-verified structure; r15 exact micro-opts).
// ---------------------------------------------------------------------------
__global__ __launch_bounds__(256) void attn_mfma(
    const __bf16* __restrict__ qkv, const int* __restrict__ ls,
    __bf16* __restrict__ out) {
  const int id = blockIdx.x;
  const int z = id >> 8, rem = id & 255;
  const int qt0 = rem & 15, h = rem >> 4, b = z;
  const int qt = z ? (15 - qt0) : qt0;
  __shared__ f32x4 lds4[2304];             // 36864 B
  char* lds = (char*)lds4;
  __bf16* Ks = (__bf16*)lds;               // [64][72]
  __bf16* Vs = (__bf16*)(lds + 9216);      // [64][72] transposed (d-major)
  __shared__ int redmin[4];
  const int t = threadIdx.x, w = t >> 6, l = t & 63;
  __bf16* Pq = (__bf16*)(lds + 18432 + w * 4608);  // [32][72] per wave
  const int r = l & 31, hi = l >> 5;
  const int qb = qt * 128, qw = qb + w * 32, qg = qw + r;
  const int Lq = ls[b*SS + qg];

  {
    int mn = Lq;
#pragma unroll
    for (int off = 1; off < 64; off <<= 1) mn = min(mn, __shfl_xor(mn, off));
    if (l == 0) redmin[w] = mn;
  }

  bf16x8 qf[4];
  {
    const __bf16* qrow = qkv + (size_t)(b*SS + qg) * 3*EE + EE + h*DD + 8*hi;
#pragma unroll
    for (int ds = 0; ds < 4; ++ds) qf[ds] = *(const bf16x8*)(qrow + 16*ds);
  }
  __syncthreads();
  const int ktmin = min(min(redmin[0], redmin[1]), min(redmin[2], redmin[3])) >> 6;
  const int ktmax = 2*qt + 1;

  f32x16 oacc[2] = {};
  float m_r = NEG_HUGE, lsum = 0.0f;       // log2 domain

  for (int kt = ktmin; kt <= ktmax; ++kt) {
    __syncthreads();
    {
      const int kr = t >> 2, c0 = (t & 3) * 16;
      const __bf16* kg = qkv + (size_t)(b*SS + kt*64 + kr) * 3*EE + h*DD + c0;
      const __bf16* vg = kg + 2*EE;
      bf16x8 k0 = *(const bf16x8*)kg;
      bf16x8 k1 = *(const bf16x8*)(kg + 8);
      bf16x8 v0 = *(const bf16x8*)vg;
      bf16x8 v1 = *(const bf16x8*)(vg + 8);
      *(bf16x8*)&Ks[kr*72 + c0]     = k0;
      *(bf16x8*)&Ks[kr*72 + c0 + 8] = k1;
      const int vc = (kr + 8*(t & 3)) & 63;
#pragma unroll
      for (int j = 0; j < 8; ++j) {
        Vs[(c0 + j)*72 + vc]     = v0[j];
        Vs[(c0 + 8 + j)*72 + vc] = v1[j];
      }
    }
    __syncthreads();

    bool act0 = (kt*64)      <= (qw + 31);
    bool act1 = (kt*64 + 32) <= (qw + 31);
    if (!act0) continue;

    f32x16 st[2];
    st[0] = (f32x16){};
    st[1] = (f32x16){};
#pragma unroll
    for (int ds = 0; ds < 4; ++ds) {
      bf16x8 kf = *(const bf16x8*)&Ks[(r)*72 + 16*ds + 8*hi];
      st[0] = __builtin_amdgcn_mfma_f32_32x32x16_bf16(kf, qf[ds], st[0], 0, 0, 0);
    }
    if (act1) {
#pragma unroll
      for (int ds = 0; ds < 4; ++ds) {
        bf16x8 kf = *(const bf16x8*)&Ks[(32 + r)*72 + 16*ds + 8*hi];
        st[1] = __builtin_amdgcn_mfma_f32_32x32x16_bf16(kf, qf[ds], st[1], 0, 0, 0);
      }
    }

    float tmax = NEG_HUGE;
#pragma unroll
    for (int kt2 = 0; kt2 < 2; ++kt2) {
#pragma unroll
      for (int reg = 0; reg < 16; ++reg) {
        const int key = kt*64 + 32*kt2 + (reg & 3) + 8*(reg >> 2) + 4*hi;
        float s = (kt2 == 0 || act1) ? st[kt2][reg] * SC_LOG2 : NEG_HUGE;
        const bool valid = (key >= Lq) && (key <= qg);
        s = valid ? s : NEG_HUGE;
        st[kt2][reg] = s;
        tmax = fmaxf(tmax, s);
      }
    }
    tmax = fmaxf(tmax, __shfl_xor(tmax, 32));
    const float m_old = m_r;
    const float m_new = fmaxf(m_r, tmax);
    m_r = m_new;
    const unsigned long long grew = __ballot(m_new != m_old);

    float psum = 0.0f;
#pragma unroll
    for (int kt2 = 0; kt2 < 2; ++kt2) {
#pragma unroll
      for (int g2 = 0; g2 < 4; ++g2) {
        bf16x4 pk;
#pragma unroll
        for (int j = 0; j < 4; ++j) {
          float p = exp2f(st[kt2][g2*4 + j] - m_new);
          psum += p;
          pk[j] = (__bf16)p;
        }
        *(bf16x4*)&Pq[r*72 + 32*kt2 + 8*g2 + 4*hi] = pk;
      }
    }
    psum += __shfl_xor(psum, 32);
    if (grew) {
      const float alpha = exp2f(m_old - m_new);
      lsum = lsum * alpha + psum;
      oacc[0] *= alpha;
      oacc[1] *= alpha;
    } else {
      lsum += psum;
    }

#pragma unroll
    for (int ks = 0; ks < 4; ++ks) {
      if (kt*64 + 16*ks > qw + 31) continue;
      bf16x8 pf = *(const bf16x8*)&Pq[r*72 + 16*ks + 8*hi];
#pragma unroll
      for (int mt = 0; mt < 2; ++mt) {
        const int d = 32*mt + r;
        const int vcol = (16*ks + 8*hi + 8*((d >> 4) & 3)) & 63;
        bf16x8 vf = *(const bf16x8*)&Vs[d*72 + vcol];
        oacc[mt] = __builtin_amdgcn_mfma_f32_32x32x16_bf16(vf, pf, oacc[mt], 0, 0, 0);
      }
    }
  }

  __syncthreads();
  float* Ot = (float*)(lds + w * 8448);        // [64][33] f32 per wave
  const float rinv = 1.0f / lsum;
#pragma unroll
  for (int mt = 0; mt < 2; ++mt)
#pragma unroll
    for (int reg = 0; reg < 16; ++reg) {
      const int d = 32*mt + (reg & 3) + 8*(reg >> 2) + 4*hi;
      Ot[d*33 + r] = oacc[mt][reg] * rinv;
    }
  __syncthreads();
  const int qr0 = l >> 4, dc = (l & 15) * 4;
#pragma unroll
  for (int it = 0; it < 8; ++it) {
    const int qr = qr0 + 4*it;
    bf16x4 ov;
    ov[0] = (__bf16)Ot[(dc+0)*33 + qr];
    ov[1] = (__bf16)Ot[(dc+1)*33 + qr];
    ov[2] = (__bf16)Ot[(dc+2)*33 + qr];
    ov[3] = (__bf16)Ot[(dc+3)*33 + qr];
    *(bf16x4*)(out + (size_t)(b*SS + qw + qr) * EE + h*DD + dc) = ov;
  }
}

// ---------------------------------------------------------------------------
extern "C" void kernel_launch(void* const* d_in, const int* in_sizes, int n_in,
                              void* d_out, int out_size, void* d_ws, size_t ws_size,
                              hipStream_t stream) {
  const int*   tokens     = (const int*)  d_in[0];
  const float* word_embed = (const float*)d_in[1];
  const float* pos_embed  = (const float*)d_in[2];
  const float* unembed_b  = (const float*)d_in[3];
  const float* kqv_w      = (const float*)d_in[4];
  const float* wo_w       = (const float*)d_in[5];
  const float* up_w       = (const float*)d_in[6];
  const float* up_b       = (const float*)d_in[7];
  const float* down_w     = (const float*)d_in[8];
  const float* down_b     = (const float*)d_in[9];
  const float* ln1_s      = (const float*)d_in[10];
  const float* ln1_b      = (const float*)d_in[11];
  const float* ln2_s      = (const float*)d_in[12];
  const float* ln2_b      = (const float*)d_in[13];
  float* logits = (float*)d_out;

  // d_out (524 MB) scratch map (all dead before the final GEMM writes logits):
  char* ob = (char*)d_out;
  __bf16* qkv  = (__bf16*)ob;                          // 24 MB
  __bf16* t0   = (__bf16*)(ob +  24ull*1024*1024);     //  8 MB
  __bf16* hbuf = (__bf16*)(ob +  32ull*1024*1024);     // 32 MB
  __bf16* ybuf = (__bf16*)(ob +  64ull*1024*1024);     //  8 MB (bf16)
  __bf16* wcvt = (__bf16*)(ob +  80ull*1024*1024);     // 50.4 MB bf16 weights
  float*  x    = (float*) (ob + 131ull*1024*1024);     // 16 MB fp32 residual
  float*  psk  = (float*) (ob + 160ull*1024*1024);     // 2 x 16 MB splitK partials
  __bf16* kqvb  = wcvt;
  __bf16* wob   = kqvb + (size_t)LL*3*EE*EE;
  __bf16* upb   = wob  + (size_t)LL*EE*EE;
  __bf16* downb = upb  + (size_t)LL*FF*EE;
  // ws: only what must survive the final GEMM (which overwrites all of d_out).
  int*    ls   = (int*)d_ws;                            // 64 KB
  __bf16* xb   = (__bf16*)((char*)d_ws + 65536);        // 8 MB
  __bf16* webf = (__bf16*)((char*)d_ws + 65536 + 8ull*1024*1024);
  const bool bigws = ws_size >= (size_t)(65536 + 8ull*1024*1024 + (size_t)VV*EE*2);

  lastart_scan<<<BB, 1024, 0, stream>>>(tokens, ls);
  embed_kernel<<<BS, 256, 0, stream>>>(tokens, ls, word_embed, pos_embed, x, xb);

  // weight pre-conversion (fp32 -> bf16)
  cvt_bf16_kernel<<<LL*3*EE*EE/2048, 256, 0, stream>>>(kqv_w,  kqvb,  LL*3*EE*EE);
  cvt_bf16_kernel<<<LL*EE*EE/2048,   256, 0, stream>>>(wo_w,   wob,   LL*EE*EE);
  cvt_bf16_kernel<<<LL*FF*EE/2048,   256, 0, stream>>>(up_w,   upb,   LL*FF*EE);
  cvt_bf16_kernel<<<LL*EE*FF/2048,   256, 0, stream>>>(down_w, downb, LL*EE*FF);
  if (bigws)
    cvt_bf16_kernel<<<VV*EE/2048, 256, 0, stream>>>(word_embed, webf, VV*EE);

  for (int l = 0; l < LL; ++l) {
    gemm_8ph<1,false,false,true><<<(BS/256)*(3*EE/256), 512, 0, stream>>>(
        xb, kqvb + (size_t)l*3*EE*EE, nullptr, qkv, 3*EE, EE, BS/256);
    attn_mfma<<<512, 256, 0, stream>>>(qkv, ls, t0);
    gemm_deep<4,2,2,false,false,true><<<(BS/128)*(EE/128), 256, 0, stream>>>(
        t0, wob + (size_t)l*EE*EE, nullptr, ybuf, EE, EE, BS/128);
    ln_res_kernel<<<BS, 256, 0, stream>>>(ybuf, x, xb, ln1_s + l*EE, ln1_b + l*EE);
    gemm_8ph<1,true,true,true><<<(BS/256)*(FF/256), 512, 0, stream>>>(
        xb, upb + (size_t)l*FF*EE, up_b + (size_t)l*FF, hbuf, FF, EE, BS/256);
    // down: split-K=2 (fills both blocks/CU slots) + fused reduce+bias
    gemm_deep_sk<4,2,2><<<2*(BS/128)*(EE/128), 256, 0, stream>>>(
        hbuf, downb + (size_t)l*EE*FF, psk, EE, FF, FF/2, BS/128, BS);
    splitk_reduce_bias<<<(BS*EE)/2048, 256, 0, stream>>>(
        psk, psk + (size_t)BS*EE, down_b + l*EE, ybuf, EE);
    ln_res_kernel<<<BS, 256, 0, stream>>>(ybuf, x, xb, ln2_s + l*EE, ln2_b + l*EE);
  }

  if (bigws) {
    gemm_8ph<8,true,false,false><<<(VV/256)*2, 512, 0, stream>>>(
        xb, webf, unembed_b, logits, VV, EE, 2);
  } else {
    gemm_fast<false,true,false,false><<<dim3(BS/128, VV/128), 256, 0, stream>>>(
        xb, word_embed, unembed_b, logits, VV, EE);
  }
}

// Round 17
// 891.811 us; speedup vs baseline: 1.0202x; 1.0202x over previous
//
#include <hip/hip_runtime.h>
#include <hip/hip_bf16.h>

#define BB 2
#define SS 2048
#define EE 1024
#define HH 16
#define DD 64
#define FF 4096
#define VV 32000
#define LL 2
#define BS (BB*SS)

#define NEG_HUGE (-3.402823466e+38f)

typedef __attribute__((ext_vector_type(4)))  float  f32x4;
typedef __attribute__((ext_vector_type(16))) float  f32x16;
typedef __attribute__((ext_vector_type(8)))  __bf16 bf16x8;
typedef __attribute__((ext_vector_type(4)))  __bf16 bf16x4;

__device__ inline bf16x8 to_bf8(float4 a, float4 b) {
  bf16x8 r;
  r[0] = (__bf16)a.x; r[1] = (__bf16)a.y; r[2] = (__bf16)a.z; r[3] = (__bf16)a.w;
  r[4] = (__bf16)b.x; r[5] = (__bf16)b.y; r[6] = (__bf16)b.z; r[7] = (__bf16)b.w;
  return r;
}

typedef const unsigned int __attribute__((address_space(1)))* gptr_t;
typedef unsigned int __attribute__((address_space(3)))* lptr_t;
__device__ inline void gload16(const void* g, void* l) {
  __builtin_amdgcn_global_load_lds((gptr_t)g, (lptr_t)l, 16, 0, 0);
}

// ---------------------------------------------------------------------------
// last_start via parallel max-scan (1 block per batch row).
// ---------------------------------------------------------------------------
__global__ __launch_bounds__(1024) void lastart_scan(
    const int* __restrict__ tokens, int* __restrict__ ls) {
  __shared__ int buf[SS];
  const int b = blockIdx.x, t = threadIdx.x;
#pragma unroll
  for (int j = 0; j < 2; ++j) {
    int i = t + j * 1024;
    buf[i] = (i > 0 && tokens[b*SS + i] == 1) ? i : 0;
  }
  __syncthreads();
  for (int off = 1; off < SS; off <<= 1) {
    int i0 = t, i1 = t + 1024;
    int v0 = (i0 >= off) ? max(buf[i0], buf[i0 - off]) : buf[i0];
    int v1 = (i1 >= off) ? max(buf[i1], buf[i1 - off]) : buf[i1];
    __syncthreads();
    buf[i0] = v0; buf[i1] = v1;
    __syncthreads();
  }
#pragma unroll
  for (int j = 0; j < 2; ++j) {
    int i = t + j * 1024;
    ls[b*SS + i] = buf[i];
  }
}

__global__ __launch_bounds__(256) void embed_kernel(
    const int* __restrict__ tokens, const int* __restrict__ ls,
    const float* __restrict__ we, const float* __restrict__ pe,
    float* __restrict__ x, __bf16* __restrict__ xb) {
  int row = blockIdx.x;
  int s = row & (SS - 1);
  int tok = tokens[row];
  int rp = s - ls[row];
  const float4* w4 = (const float4*)(we + (size_t)tok * EE);
  const float4* p4 = (const float4*)(pe + (size_t)rp * EE);
  float4 a = w4[threadIdx.x];
  float4 b = p4[threadIdx.x];
  float4 o; o.x = a.x + b.x; o.y = a.y + b.y; o.z = a.z + b.z; o.w = a.w + b.w;
  ((float4*)(x + (size_t)row * EE))[threadIdx.x] = o;
  bf16x4 ob4;
  ob4[0] = (__bf16)o.x; ob4[1] = (__bf16)o.y; ob4[2] = (__bf16)o.z; ob4[3] = (__bf16)o.w;
  *(bf16x4*)(xb + (size_t)row * EE + threadIdx.x * 4) = ob4;
}

// ---------------------------------------------------------------------------
__global__ __launch_bounds__(256) void cvt_bf16_kernel(
    const float* __restrict__ src, __bf16* __restrict__ dst, int n) {
  int i = (blockIdx.x * 256 + threadIdx.x) * 8;
  if (i + 8 > n) return;
  float4 a = *(const float4*)(src + i);
  float4 b = *(const float4*)(src + i + 4);
  *(bf16x8*)(dst + i) = to_bf8(a, b);
}

// ---------------------------------------------------------------------------
// Persistent 8-phase 256x256 GEMM (r9-verified schedule).
// ---------------------------------------------------------------------------
__device__ inline void stage_half8(const __bf16* __restrict__ base,
                                   __bf16* region, int K, int kofs,
                                   int col8, int srow, int sdst) {
#pragma unroll
  for (int p = 0; p < 2; ++p)
    gload16(base + (size_t)(p * 128 + srow) * K + kofs + col8,
            region + p * 4096 + sdst);
}

template<int NMT, bool BIAS, bool RELU, bool OUTBF16>
__global__ __launch_bounds__(512, 2) void gemm_8ph(
    const __bf16* __restrict__ A, const __bf16* __restrict__ W,
    const float* __restrict__ bias, void* __restrict__ Cv,
    int N, int K, int nmg) {
  __shared__ __bf16 lds[8][8192];              // [c*4 + ab*2 + kh][256*32]
  const int t = threadIdx.x, l = t & 63, w = t >> 6;
  const int nwg = gridDim.x, orig = blockIdx.x;
  const int q = nwg >> 3, r = nwg & 7, xcd = orig & 7, pos = orig >> 3;
  const int wgid = (xcd < r ? xcd*(q+1) : r*(q+1) + (xcd-r)*q) + pos;
  const int mgrp = wgid % nmg, n0 = (wgid / nmg) * 256;
  const int wm = w >> 2, wn = w & 3;
  const int fr = l & 15, c8 = l >> 4;
  const int swz = (c8 ^ ((fr >> 1) & 3)) * 8;
  const int roA = (wm*128 + fr) * 32 + swz;
  const int roB = (wn*64  + fr) * 32 + swz;
  const int col8 = ((t & 3) ^ ((t >> 3) & 3)) * 8;
  const int srow = t >> 2;
  const int sdst = (t >> 6) * 512;

  const __bf16* Wb = W + (size_t)n0 * K;
  const int ng = NMT * 16;

  float bv[4];
#pragma unroll
  for (int j = 0; j < 4; ++j) bv[j] = BIAS ? bias[n0 + wn*64 + fr + j*16] : 0.0f;

  f32x4 acc[8][4] = {};

#define ABASE(g2) (A + (size_t)(mgrp*NMT + ((g2) >> 4)) * 256 * K)
#define KOFS(g2)  (((g2) & 15) * 64)

  stage_half8(ABASE(0), &lds[0][0], K, 0,  col8, srow, sdst);
  stage_half8(Wb,       &lds[2][0], K, 0,  col8, srow, sdst);
  stage_half8(ABASE(0), &lds[1][0], K, 32, col8, srow, sdst);
  stage_half8(Wb,       &lds[3][0], K, 32, col8, srow, sdst);
  stage_half8(ABASE(1), &lds[4][0], K, 64, col8, srow, sdst);
  stage_half8(Wb,       &lds[6][0], K, 64, col8, srow, sdst);
  asm volatile("s_waitcnt vmcnt(4)" ::: "memory");
  __builtin_amdgcn_s_barrier();

  for (int g = 0; g < ng; ++g) {
    const int c = g & 1;
    const int rA = c*4, rB = c*4 + 2;
    bf16x8 afr0[4], afr1[4], bfr[4];
    // ---- P1: kh0 — read B, A-lo, A-hi (hi completes under MFMA) ----
#pragma unroll
    for (int j = 0; j < 4; ++j) bfr[j]  = *(const bf16x8*)&lds[rB][roB + j*512];
#pragma unroll
    for (int i = 0; i < 4; ++i) afr0[i] = *(const bf16x8*)&lds[rA][roA + i*512];
#pragma unroll
    for (int i = 0; i < 4; ++i) afr1[i] = *(const bf16x8*)&lds[rA][roA + (i+4)*512];
    if (g + 1 < ng)
      stage_half8(ABASE(g+1), &lds[(c^1)*4 + 1][0], K, KOFS(g+1) + 32, col8, srow, sdst);
    __builtin_amdgcn_s_barrier();
    __builtin_amdgcn_s_setprio(1);
#pragma unroll
    for (int i = 0; i < 4; ++i)
#pragma unroll
      for (int j = 0; j < 4; ++j)
        acc[i][j] = __builtin_amdgcn_mfma_f32_16x16x32_bf16(afr0[i], bfr[j], acc[i][j], 0, 0, 0);
    __builtin_amdgcn_s_setprio(0);
    __builtin_amdgcn_s_barrier();
    // ---- P2: kh0 hi — pure MFMA ----
    if (g + 1 < ng)
      stage_half8(Wb, &lds[(c^1)*4 + 3][0], K, KOFS(g+1) + 32, col8, srow, sdst);
    __builtin_amdgcn_s_barrier();
    __builtin_amdgcn_s_setprio(1);
#pragma unroll
    for (int i = 0; i < 4; ++i)
#pragma unroll
      for (int j = 0; j < 4; ++j)
        acc[i+4][j] = __builtin_amdgcn_mfma_f32_16x16x32_bf16(afr1[i], bfr[j], acc[i+4][j], 0, 0, 0);
    __builtin_amdgcn_s_setprio(0);
    if (g < ng - 1) { asm volatile("s_waitcnt vmcnt(8)" ::: "memory"); }
    else            { asm volatile("s_waitcnt vmcnt(0)" ::: "memory"); }
    __builtin_amdgcn_s_barrier();
    // ---- P3: kh1 — read B, A-lo, A-hi ----
#pragma unroll
    for (int j = 0; j < 4; ++j) bfr[j]  = *(const bf16x8*)&lds[rB + 1][roB + j*512];
#pragma unroll
    for (int i = 0; i < 4; ++i) afr0[i] = *(const bf16x8*)&lds[rA + 1][roA + i*512];
#pragma unroll
    for (int i = 0; i < 4; ++i) afr1[i] = *(const bf16x8*)&lds[rA + 1][roA + (i+4)*512];
    if (g + 2 < ng)
      stage_half8(ABASE(g+2), &lds[c*4][0], K, KOFS(g+2), col8, srow, sdst);
    __builtin_amdgcn_s_barrier();
    __builtin_amdgcn_s_setprio(1);
#pragma unroll
    for (int i = 0; i < 4; ++i)
#pragma unroll
      for (int j = 0; j < 4; ++j)
        acc[i][j] = __builtin_amdgcn_mfma_f32_16x16x32_bf16(afr0[i], bfr[j], acc[i][j], 0, 0, 0);
    __builtin_amdgcn_s_setprio(0);
    __builtin_amdgcn_s_barrier();
    // ---- P4: kh1 hi — pure MFMA ----
    if (g + 2 < ng)
      stage_half8(Wb, &lds[c*4 + 2][0], K, KOFS(g+2), col8, srow, sdst);
    __builtin_amdgcn_s_barrier();
    __builtin_amdgcn_s_setprio(1);
#pragma unroll
    for (int i = 0; i < 4; ++i)
#pragma unroll
      for (int j = 0; j < 4; ++j)
        acc[i+4][j] = __builtin_amdgcn_mfma_f32_16x16x32_bf16(afr1[i], bfr[j], acc[i+4][j], 0, 0, 0);
    __builtin_amdgcn_s_setprio(0);
    if (g < ng - 2)       { asm volatile("s_waitcnt vmcnt(8)" ::: "memory"); }
    else if (g == ng - 2) { asm volatile("s_waitcnt vmcnt(4)" ::: "memory"); }
    __builtin_amdgcn_s_barrier();
    // ---- per-tile epilogue (regs only) ----
    if ((g & 15) == 15) {
      const int orow = (mgrp*NMT + (g >> 4)) * 256 + wm*128 + c8 * 4;
      const int ocol = n0 + wn*64 + fr;
#pragma unroll
      for (int i = 0; i < 8; ++i)
#pragma unroll
        for (int j = 0; j < 4; ++j) {
#pragma unroll
          for (int rr = 0; rr < 4; ++rr) {
            float v = acc[i][j][rr] + bv[j];
            if (RELU) v = fmaxf(v, 0.0f);
            if (OUTBF16)
              ((__bf16*)Cv)[(size_t)(orow + i*16 + rr) * N + ocol + j*16] = (__bf16)v;
            else
              ((float*)Cv)[(size_t)(orow + i*16 + rr) * N + ocol + j*16] = v;
          }
          acc[i][j] = (f32x4){};
        }
    }
  }
#undef ABASE
#undef KOFS
}

// ---------------------------------------------------------------------------
// Deep-prefetch 128x128 GEMM (r6-verified; wo/down shapes).
// ---------------------------------------------------------------------------
template<int T, int BM>
__device__ inline void stage2(const __bf16* __restrict__ Ab,
                              const __bf16* __restrict__ Wb,
                              __bf16* la, __bf16* lb, int K, int k0, int t) {
  const int col8 = (t & 3) ^ ((t >> 3) & 3);
  const int cofs = k0 + col8 * 8;
  const int wbase = (t >> 6) * 512;
#pragma unroll
  for (int p = 0; p < (BM * 32) / (T * 8); ++p) {
    const int row = p * (T >> 2) + (t >> 2);
    gload16(Ab + (size_t)row * K + cofs, la + p * T * 8 + wbase);
    gload16(Wb + (size_t)row * K + cofs, lb + p * T * 8 + wbase);
  }
}

template<int RW, int WM, int WN, bool BIAS, bool RELU, bool OUTBF16>
__global__ __launch_bounds__(WM*WN*64, 2) void gemm_deep(
    const __bf16* __restrict__ A, const __bf16* __restrict__ W,
    const float* __restrict__ bias, void* __restrict__ Cv,
    int N, int K, int nbx) {
  constexpr int T  = WM * WN * 64;
  constexpr int BM = WM * RW * 16;
  __shared__ __bf16 lds[4][2][BM * 32];
  const int t = threadIdx.x, l = t & 63, w = t >> 6;
  const int nwg = gridDim.x, orig = blockIdx.x;
  const int q = nwg >> 3, r = nwg & 7, xcd = orig & 7, pos = orig >> 3;
  const int wgid = (xcd < r ? xcd*(q+1) : r*(q+1) + (xcd-r)*q) + pos;
  const int m0 = (wgid % nbx) * BM, n0 = (wgid / nbx) * BM;
  const int wm = w / WN, wn = w % WN;
  const int fr = l & 15, c8 = l >> 4;
  const int slot = (c8 ^ ((fr >> 1) & 3)) * 8;

  const __bf16* Abase = A + (size_t)m0 * K;
  const __bf16* Wbase = W + (size_t)n0 * K;

  f32x4 acc[RW][4] = {};

  const int nk = K >> 5;
  stage2<T,BM>(Abase, Wbase, &lds[0][0][0], &lds[0][1][0], K, 0,  t);
  stage2<T,BM>(Abase, Wbase, &lds[1][0][0], &lds[1][1][0], K, 32, t);
  stage2<T,BM>(Abase, Wbase, &lds[2][0][0], &lds[2][1][0], K, 64, t);

  for (int kt = 0; kt < nk; ++kt) {
    const int cur = kt & 3;
    if (kt + 3 < nk) {
      const int nb = (kt + 3) & 3;
      stage2<T,BM>(Abase, Wbase, &lds[nb][0][0], &lds[nb][1][0], K, (kt+3)*32, t);
      asm volatile("s_waitcnt vmcnt(8)" ::: "memory");
    } else if (kt + 2 < nk) {
      asm volatile("s_waitcnt vmcnt(8)" ::: "memory");
    } else if (kt + 1 < nk) {
      asm volatile("s_waitcnt vmcnt(4)" ::: "memory");
    } else {
      asm volatile("s_waitcnt vmcnt(0)" ::: "memory");
    }
    __builtin_amdgcn_s_barrier();
    __builtin_amdgcn_sched_barrier(0);
    const __bf16* La = &lds[cur][0][0];
    const __bf16* Lb = &lds[cur][1][0];
    bf16x8 bfr[4];
#pragma unroll
    for (int j = 0; j < 4; ++j)
      bfr[j] = *(const bf16x8*)&Lb[(wn*64 + j*16 + fr) * 32 + slot];
    __builtin_amdgcn_s_setprio(1);
#pragma unroll
    for (int i = 0; i < RW; ++i) {
      bf16x8 af = *(const bf16x8*)&La[(wm*(RW*16) + i*16 + fr) * 32 + slot];
#pragma unroll
      for (int j = 0; j < 4; ++j)
        acc[i][j] = __builtin_amdgcn_mfma_f32_16x16x32_bf16(af, bfr[j], acc[i][j], 0, 0, 0);
    }
    __builtin_amdgcn_s_setprio(0);
    __builtin_amdgcn_sched_barrier(0);
    __builtin_amdgcn_s_barrier();
    __builtin_amdgcn_sched_barrier(0);
  }

  const int orow = m0 + wm*(RW*16) + c8 * 4;
  const int ocol = n0 + wn*64 + fr;
#pragma unroll
  for (int i = 0; i < RW; ++i)
#pragma unroll
    for (int j = 0; j < 4; ++j) {
      const int col = ocol + j * 16;
      const float bv = BIAS ? bias[col] : 0.0f;
#pragma unroll
      for (int rr = 0; rr < 4; ++rr) {
        float v = acc[i][j][rr] + bv;
        if (RELU) v = fmaxf(v, 0.0f);
        if (OUTBF16)
          ((__bf16*)Cv)[(size_t)(orow + i*16 + rr) * N + col] = (__bf16)v;
        else
          ((float*)Cv)[(size_t)(orow + i*16 + rr) * N + col] = v;
      }
    }
}

// ---------------------------------------------------------------------------
// 128x128 2-phase GEMM (fallback unembed only: fp32 W reg-staged).
// ---------------------------------------------------------------------------
template<bool WBF16, bool BIAS, bool RELU, bool OUTBF16>
__global__ __launch_bounds__(256) void gemm_fast(
    const __bf16* __restrict__ A, const void* __restrict__ Wv,
    const float* __restrict__ bias, void* __restrict__ Cv, int N, int K) {
  __shared__ __bf16 As[128][32];
  __shared__ __bf16 Bs[128][32];
  const int t = threadIdx.x;
  const int m0 = blockIdx.x * 128, n0 = blockIdx.y * 128;
  const int l = t & 63, w = t >> 6;
  const int wm = (w >> 1) * 64, wn = (w & 1) * 64;
  const int fr = l & 15, fk = (l >> 4) * 8;
  const int crow = l >> 2, ccol = (l & 3) * 8;
  const int wrow = t >> 1, wcol = (t & 1) * 16;

  const __bf16* Wb = (const __bf16*)Wv;
  const float*  Wf = (const float*)Wv;

  f32x4 acc[4][4] = {};

  for (int k0 = 0; k0 < K; k0 += 32) {
    float4 wf0, wf1, wf2, wf3;
    if (!WBF16) {
      const float* wp = Wf + (size_t)(n0 + wrow) * K + k0 + wcol;
      wf0 = *(const float4*)(wp);
      wf1 = *(const float4*)(wp + 4);
      wf2 = *(const float4*)(wp + 8);
      wf3 = *(const float4*)(wp + 12);
    }
    __syncthreads();
#pragma unroll
    for (int i = 0; i < 2; ++i) {
      const int c = 2 * w + i;
      gload16(A + (size_t)(m0 + c*16 + crow) * K + k0 + ccol, (__bf16*)As + c*512);
      if (WBF16)
        gload16(Wb + (size_t)(n0 + c*16 + crow) * K + k0 + ccol, (__bf16*)Bs + c*512);
    }
    if (!WBF16) {
      *(bf16x8*)&Bs[wrow][wcol]     = to_bf8(wf0, wf1);
      *(bf16x8*)&Bs[wrow][wcol + 8] = to_bf8(wf2, wf3);
    }
    __syncthreads();
    bf16x8 af[4], bf[4];
#pragma unroll
    for (int i = 0; i < 4; ++i) af[i] = *(const bf16x8*)&As[wm + i*16 + fr][fk];
#pragma unroll
    for (int j = 0; j < 4; ++j) bf[j] = *(const bf16x8*)&Bs[wn + j*16 + fr][fk];
#pragma unroll
    for (int i = 0; i < 4; ++i)
#pragma unroll
      for (int j = 0; j < 4; ++j)
        acc[i][j] = __builtin_amdgcn_mfma_f32_16x16x32_bf16(af[i], bf[j], acc[i][j], 0, 0, 0);
  }

  const int orow = m0 + wm + (l >> 4) * 4;
  const int ocol = n0 + wn + fr;
#pragma unroll
  for (int i = 0; i < 4; ++i)
#pragma unroll
    for (int j = 0; j < 4; ++j) {
      const int col = ocol + j * 16;
      const float bv = BIAS ? bias[col] : 0.0f;
#pragma unroll
      for (int r = 0; r < 4; ++r) {
        float v = acc[i][j][r] + bv;
        if (RELU) v = fmaxf(v, 0.0f);
        if (OUTBF16)
          ((__bf16*)Cv)[(size_t)(orow + i*16 + r) * N + col] = (__bf16)v;
        else
          ((float*)Cv)[(size_t)(orow + i*16 + r) * N + col] = v;
      }
    }
}

// ---------------------------------------------------------------------------
// x = LN(y + x) * s + b ; y is bf16. Also emit bf16 copy xb.
// ---------------------------------------------------------------------------
__global__ __launch_bounds__(256) void ln_res_kernel(
    const __bf16* __restrict__ y, float* __restrict__ x, __bf16* __restrict__ xb,
    const float* __restrict__ sc, const float* __restrict__ bs) {
  __shared__ float red[8];
  int row = blockIdx.x, t = threadIdx.x;
  bf16x4 a4 = *(const bf16x4*)(y + (size_t)row * EE + t * 4);
  float4* x4 = (float4*)(x + (size_t)row * EE);
  float4 c = x4[t];
  float v0 = (float)a4[0] + c.x, v1 = (float)a4[1] + c.y;
  float v2 = (float)a4[2] + c.z, v3 = (float)a4[3] + c.w;
  float s = v0 + v1 + v2 + v3;
  float q = v0*v0 + v1*v1 + v2*v2 + v3*v3;
#pragma unroll
  for (int off = 32; off; off >>= 1) {
    s += __shfl_xor(s, off);
    q += __shfl_xor(q, off);
  }
  int w = t >> 6;
  if ((t & 63) == 0) { red[w] = s; red[4 + w] = q; }
  __syncthreads();
  s = red[0] + red[1] + red[2] + red[3];
  q = red[4] + red[5] + red[6] + red[7];
  float mean = s * (1.0f / EE);
  float var  = q * (1.0f / EE) - mean * mean;
  float r = 1.0f / sqrtf(var + 1e-6f);
  float4 ss = ((const float4*)sc)[t];
  float4 bb = ((const float4*)bs)[t];
  float4 o;
  o.x = (v0 - mean) * r * ss.x + bb.x;
  o.y = (v1 - mean) * r * ss.y + bb.y;
  o.z = (v2 - mean) * r * ss.z + bb.z;
  o.w = (v3 - mean) * r * ss.w + bb.w;
  x4[t] = o;
  bf16x4 ob4;
  ob4[0] = (__bf16)o.x; ob4[1] = (__bf16)o.y; ob4[2] = (__bf16)o.z; ob4[3] = (__bf16)o.w;
  *(bf16x4*)(xb + (size_t)row * EE + t * 4) = ob4;
}

// ---------------------------------------------------------------------------
// MFMA flash attention (r8/r11-verified: 128-query tile, 4 waves, 256 thr,
// 1-D grid 512 with z-pairing).
// ---------------------------------------------------------------------------
__global__ __launch_bounds__(256) void attn_mfma(
    const __bf16* __restrict__ qkv, const int* __restrict__ ls,
    __bf16* __restrict__ out) {
  const int id = blockIdx.x;
  const int z = id >> 8, rem = id & 255;
  const int qt0 = rem & 15, h = rem >> 4, b = z;
  const int qt = z ? (15 - qt0) : qt0;
  __shared__ f32x4 lds4[2304];             // 36864 B
  char* lds = (char*)lds4;
  __bf16* Ks = (__bf16*)lds;               // [64][72]
  __bf16* Vs = (__bf16*)(lds + 9216);      // [64][72] transposed (d-major)
  __shared__ int redmin[4];
  const int t = threadIdx.x, w = t >> 6, l = t & 63;
  __bf16* Pq = (__bf16*)(lds + 18432 + w * 4608);  // [32][72] per wave
  const int r = l & 31, hi = l >> 5;
  const int qb = qt * 128, qw = qb + w * 32, qg = qw + r;
  const int Lq = ls[b*SS + qg];

  {
    int mn = Lq;
#pragma unroll
    for (int off = 1; off < 64; off <<= 1) mn = min(mn, __shfl_xor(mn, off));
    if (l == 0) redmin[w] = mn;
  }

  bf16x8 qf[4];
  {
    const __bf16* qrow = qkv + (size_t)(b*SS + qg) * 3*EE + EE + h*DD + 8*hi;
#pragma unroll
    for (int ds = 0; ds < 4; ++ds) qf[ds] = *(const bf16x8*)(qrow + 16*ds);
  }
  __syncthreads();
  const int ktmin = min(min(redmin[0], redmin[1]), min(redmin[2], redmin[3])) >> 6;
  const int ktmax = 2*qt + 1;

  f32x16 oacc[2] = {};
  float m_r = NEG_HUGE, lsum = 0.0f;

  for (int kt = ktmin; kt <= ktmax; ++kt) {
    __syncthreads();
    {
      const int kr = t >> 2, c0 = (t & 3) * 16;
      const __bf16* kg = qkv + (size_t)(b*SS + kt*64 + kr) * 3*EE + h*DD + c0;
      const __bf16* vg = kg + 2*EE;
      bf16x8 k0 = *(const bf16x8*)kg;
      bf16x8 k1 = *(const bf16x8*)(kg + 8);
      bf16x8 v0 = *(const bf16x8*)vg;
      bf16x8 v1 = *(const bf16x8*)(vg + 8);
      *(bf16x8*)&Ks[kr*72 + c0]     = k0;
      *(bf16x8*)&Ks[kr*72 + c0 + 8] = k1;
      const int vc = (kr + 8*(t & 3)) & 63;
#pragma unroll
      for (int j = 0; j < 8; ++j) {
        Vs[(c0 + j)*72 + vc]     = v0[j];
        Vs[(c0 + 8 + j)*72 + vc] = v1[j];
      }
    }
    __syncthreads();

    bool act0 = (kt*64)      <= (qw + 31);
    bool act1 = (kt*64 + 32) <= (qw + 31);
    if (!act0) continue;

    f32x16 st[2];
    st[0] = (f32x16){};
    st[1] = (f32x16){};
#pragma unroll
    for (int ds = 0; ds < 4; ++ds) {
      bf16x8 kf = *(const bf16x8*)&Ks[(r)*72 + 16*ds + 8*hi];
      st[0] = __builtin_amdgcn_mfma_f32_32x32x16_bf16(kf, qf[ds], st[0], 0, 0, 0);
    }
    if (act1) {
#pragma unroll
      for (int ds = 0; ds < 4; ++ds) {
        bf16x8 kf = *(const bf16x8*)&Ks[(32 + r)*72 + 16*ds + 8*hi];
        st[1] = __builtin_amdgcn_mfma_f32_32x32x16_bf16(kf, qf[ds], st[1], 0, 0, 0);
      }
    }

    float tmax = NEG_HUGE;
#pragma unroll
    for (int kt2 = 0; kt2 < 2; ++kt2) {
#pragma unroll
      for (int reg = 0; reg < 16; ++reg) {
        const int key = kt*64 + 32*kt2 + (reg & 3) + 8*(reg >> 2) + 4*hi;
        float s = (kt2 == 0 || act1) ? st[kt2][reg] * 0.125f : NEG_HUGE;
        const bool valid = (key >= Lq) && (key <= qg);
        s = valid ? s : NEG_HUGE;
        st[kt2][reg] = s;
        tmax = fmaxf(tmax, s);
      }
    }
    tmax = fmaxf(tmax, __shfl_xor(tmax, 32));
    const float m_new = fmaxf(m_r, tmax);
    const float alpha = __expf(m_r - m_new);
    m_r = m_new;

    float psum = 0.0f;
#pragma unroll
    for (int kt2 = 0; kt2 < 2; ++kt2) {
#pragma unroll
      for (int g2 = 0; g2 < 4; ++g2) {
        bf16x4 pk;
#pragma unroll
        for (int j = 0; j < 4; ++j) {
          float p = __expf(st[kt2][g2*4 + j] - m_new);
          psum += p;
          pk[j] = (__bf16)p;
        }
        *(bf16x4*)&Pq[r*72 + 32*kt2 + 8*g2 + 4*hi] = pk;
      }
    }
    psum += __shfl_xor(psum, 32);
    lsum = lsum * alpha + psum;
    oacc[0] *= alpha;
    oacc[1] *= alpha;

#pragma unroll
    for (int ks = 0; ks < 4; ++ks) {
      if (kt*64 + 16*ks > qw + 31) continue;
      bf16x8 pf = *(const bf16x8*)&Pq[r*72 + 16*ks + 8*hi];
#pragma unroll
      for (int mt = 0; mt < 2; ++mt) {
        const int d = 32*mt + r;
        const int vcol = (16*ks + 8*hi + 8*((d >> 4) & 3)) & 63;
        bf16x8 vf = *(const bf16x8*)&Vs[d*72 + vcol];
        oacc[mt] = __builtin_amdgcn_mfma_f32_32x32x16_bf16(vf, pf, oacc[mt], 0, 0, 0);
      }
    }
  }

  __syncthreads();
  float* Ot = (float*)(lds + w * 8448);        // [64][33] f32 per wave
  const float rinv = 1.0f / lsum;
#pragma unroll
  for (int mt = 0; mt < 2; ++mt)
#pragma unroll
    for (int reg = 0; reg < 16; ++reg) {
      const int d = 32*mt + (reg & 3) + 8*(reg >> 2) + 4*hi;
      Ot[d*33 + r] = oacc[mt][reg] * rinv;
    }
  __syncthreads();
  const int qr0 = l >> 4, dc = (l & 15) * 4;
#pragma unroll
  for (int it = 0; it < 8; ++it) {
    const int qr = qr0 + 4*it;
    bf16x4 ov;
    ov[0] = (__bf16)Ot[(dc+0)*33 + qr];
    ov[1] = (__bf16)Ot[(dc+1)*33 + qr];
    ov[2] = (__bf16)Ot[(dc+2)*33 + qr];
    ov[3] = (__bf16)Ot[(dc+3)*33 + qr];
    *(bf16x4*)(out + (size_t)(b*SS + qw + qr) * EE + h*DD + dc) = ov;
  }
}

// ---------------------------------------------------------------------------
extern "C" void kernel_launch(void* const* d_in, const int* in_sizes, int n_in,
                              void* d_out, int out_size, void* d_ws, size_t ws_size,
                              hipStream_t stream) {
  const int*   tokens     = (const int*)  d_in[0];
  const float* word_embed = (const float*)d_in[1];
  const float* pos_embed  = (const float*)d_in[2];
  const float* unembed_b  = (const float*)d_in[3];
  const float* kqv_w      = (const float*)d_in[4];
  const float* wo_w       = (const float*)d_in[5];
  const float* up_w       = (const float*)d_in[6];
  const float* up_b       = (const float*)d_in[7];
  const float* down_w     = (const float*)d_in[8];
  const float* down_b     = (const float*)d_in[9];
  const float* ln1_s      = (const float*)d_in[10];
  const float* ln1_b      = (const float*)d_in[11];
  const float* ln2_s      = (const float*)d_in[12];
  const float* ln2_b      = (const float*)d_in[13];
  float* logits = (float*)d_out;

  // d_out (524 MB) scratch map (all dead before the final GEMM writes logits):
  char* ob = (char*)d_out;
  __bf16* qkv  = (__bf16*)ob;                          // 24 MB
  __bf16* t0   = (__bf16*)(ob +  24ull*1024*1024);     //  8 MB
  __bf16* hbuf = (__bf16*)(ob +  32ull*1024*1024);     // 32 MB
  __bf16* ybuf = (__bf16*)(ob +  64ull*1024*1024);     //  8 MB (bf16)
  __bf16* wcvt = (__bf16*)(ob +  80ull*1024*1024);     // 50.4 MB bf16 weights
  float*  x    = (float*) (ob + 131ull*1024*1024);     // 16 MB fp32 residual
  __bf16* kqvb  = wcvt;
  __bf16* wob   = kqvb + (size_t)LL*3*EE*EE;
  __bf16* upb   = wob  + (size_t)LL*EE*EE;
  __bf16* downb = upb  + (size_t)LL*FF*EE;
  // ws: only what must survive the final GEMM (which overwrites all of d_out).
  int*    ls   = (int*)d_ws;                            // 64 KB
  __bf16* xb   = (__bf16*)((char*)d_ws + 65536);        // 8 MB
  __bf16* webf = (__bf16*)((char*)d_ws + 65536 + 8ull*1024*1024);
  const bool bigws = ws_size >= (size_t)(65536 + 8ull*1024*1024 + (size_t)VV*EE*2);

  lastart_scan<<<BB, 1024, 0, stream>>>(tokens, ls);
  embed_kernel<<<BS, 256, 0, stream>>>(tokens, ls, word_embed, pos_embed, x, xb);

  // weight pre-conversion (fp32 -> bf16)
  cvt_bf16_kernel<<<LL*3*EE*EE/2048, 256, 0, stream>>>(kqv_w,  kqvb,  LL*3*EE*EE);
  cvt_bf16_kernel<<<LL*EE*EE/2048,   256, 0, stream>>>(wo_w,   wob,   LL*EE*EE);
  cvt_bf16_kernel<<<LL*FF*EE/2048,   256, 0, stream>>>(up_w,   upb,   LL*FF*EE);
  cvt_bf16_kernel<<<LL*EE*FF/2048,   256, 0, stream>>>(down_w, downb, LL*EE*FF);
  if (bigws)
    cvt_bf16_kernel<<<VV*EE/2048, 256, 0, stream>>>(word_embed, webf, VV*EE);

  for (int l = 0; l < LL; ++l) {
    gemm_8ph<1,false,false,true><<<(BS/256)*(3*EE/256), 512, 0, stream>>>(
        xb, kqvb + (size_t)l*3*EE*EE, nullptr, qkv, 3*EE, EE, BS/256);
    attn_mfma<<<512, 256, 0, stream>>>(qkv, ls, t0);
    gemm_deep<4,2,2,false,false,true><<<(BS/128)*(EE/128), 256, 0, stream>>>(
        t0, wob + (size_t)l*EE*EE, nullptr, ybuf, EE, EE, BS/128);
    ln_res_kernel<<<BS, 256, 0, stream>>>(ybuf, x, xb, ln1_s + l*EE, ln1_b + l*EE);
    gemm_8ph<1,true,true,true><<<(BS/256)*(FF/256), 512, 0, stream>>>(
        xb, upb + (size_t)l*FF*EE, up_b + (size_t)l*FF, hbuf, FF, EE, BS/256);
    gemm_deep<4,2,2,true,false,true><<<(BS/128)*(EE/128), 256, 0, stream>>>(
        hbuf, downb + (size_t)l*EE*FF, down_b + (size_t)l*EE, ybuf, EE, FF, BS/128);
    ln_res_kernel<<<BS, 256, 0, stream>>>(ybuf, x, xb, ln2_s + l*EE, ln2_b + l*EE);
  }

  if (bigws) {
    gemm_8ph<8,true,false,false><<<(VV/256)*2, 512, 0, stream>>>(
        xb, webf, unembed_b, logits, VV, EE, 2);
  } else {
    gemm_fast<false,true,false,false><<<dim3(BS/128, VV/128), 256, 0, stream>>>(
        xb, word_embed, unembed_b, logits, VV, EE);
  }
}

// Round 18
// 874.007 us; speedup vs baseline: 1.0410x; 1.0204x over previous
//
#include <hip/hip_runtime.h>
#include <hip/hip_bf16.h>

#define BB 2
#define SS 2048
#define EE 1024
#define HH 16
#define DD 64
#define FF 4096
#define VV 32000
#define LL 2
#define BS (BB*SS)

#define NEG_HUGE (-3.402823466e+38f)

typedef __attribute__((ext_vector_type(4)))  float  f32x4;
typedef __attribute__((ext_vector_type(16))) float  f32x16;
typedef __attribute__((ext_vector_type(8)))  __bf16 bf16x8;
typedef __attribute__((ext_vector_type(4)))  __bf16 bf16x4;

__device__ inline bf16x8 to_bf8(float4 a, float4 b) {
  bf16x8 r;
  r[0] = (__bf16)a.x; r[1] = (__bf16)a.y; r[2] = (__bf16)a.z; r[3] = (__bf16)a.w;
  r[4] = (__bf16)b.x; r[5] = (__bf16)b.y; r[6] = (__bf16)b.z; r[7] = (__bf16)b.w;
  return r;
}

typedef const unsigned int __attribute__((address_space(1)))* gptr_t;
typedef unsigned int __attribute__((address_space(3)))* lptr_t;
__device__ inline void gload16(const void* g, void* l) {
  __builtin_amdgcn_global_load_lds((gptr_t)g, (lptr_t)l, 16, 0, 0);
}

// ---------------------------------------------------------------------------
// last_start via parallel max-scan (1 block per batch row).
// ---------------------------------------------------------------------------
__global__ __launch_bounds__(1024) void lastart_scan(
    const int* __restrict__ tokens, int* __restrict__ ls) {
  __shared__ int buf[SS];
  const int b = blockIdx.x, t = threadIdx.x;
#pragma unroll
  for (int j = 0; j < 2; ++j) {
    int i = t + j * 1024;
    buf[i] = (i > 0 && tokens[b*SS + i] == 1) ? i : 0;
  }
  __syncthreads();
  for (int off = 1; off < SS; off <<= 1) {
    int i0 = t, i1 = t + 1024;
    int v0 = (i0 >= off) ? max(buf[i0], buf[i0 - off]) : buf[i0];
    int v1 = (i1 >= off) ? max(buf[i1], buf[i1 - off]) : buf[i1];
    __syncthreads();
    buf[i0] = v0; buf[i1] = v1;
    __syncthreads();
  }
#pragma unroll
  for (int j = 0; j < 2; ++j) {
    int i = t + j * 1024;
    ls[b*SS + i] = buf[i];
  }
}

// x[b,s,:] = bf16(word_embed[tok] + pos_embed[s - ls])  (bf16 residual)
__global__ __launch_bounds__(256) void embed_kernel(
    const int* __restrict__ tokens, const int* __restrict__ ls,
    const float* __restrict__ we, const float* __restrict__ pe,
    __bf16* __restrict__ xb) {
  int row = blockIdx.x;
  int s = row & (SS - 1);
  int tok = tokens[row];
  int rp = s - ls[row];
  const float4* w4 = (const float4*)(we + (size_t)tok * EE);
  const float4* p4 = (const float4*)(pe + (size_t)rp * EE);
  float4 a = w4[threadIdx.x];
  float4 b = p4[threadIdx.x];
  bf16x4 ob4;
  ob4[0] = (__bf16)(a.x + b.x); ob4[1] = (__bf16)(a.y + b.y);
  ob4[2] = (__bf16)(a.z + b.z); ob4[3] = (__bf16)(a.w + b.w);
  *(bf16x4*)(xb + (size_t)row * EE + threadIdx.x * 4) = ob4;
}

// ---------------------------------------------------------------------------
__global__ __launch_bounds__(256) void cvt_bf16_kernel(
    const float* __restrict__ src, __bf16* __restrict__ dst, int n) {
  int i = (blockIdx.x * 256 + threadIdx.x) * 8;
  if (i + 8 > n) return;
  float4 a = *(const float4*)(src + i);
  float4 b = *(const float4*)(src + i + 4);
  *(bf16x8*)(dst + i) = to_bf8(a, b);
}

// ---------------------------------------------------------------------------
// Persistent 8-phase 256x256 GEMM (r9-verified schedule).
// ---------------------------------------------------------------------------
__device__ inline void stage_half8(const __bf16* __restrict__ base,
                                   __bf16* region, int K, int kofs,
                                   int col8, int srow, int sdst) {
#pragma unroll
  for (int p = 0; p < 2; ++p)
    gload16(base + (size_t)(p * 128 + srow) * K + kofs + col8,
            region + p * 4096 + sdst);
}

template<int NMT, bool BIAS, bool RELU, bool OUTBF16>
__global__ __launch_bounds__(512, 2) void gemm_8ph(
    const __bf16* __restrict__ A, const __bf16* __restrict__ W,
    const float* __restrict__ bias, void* __restrict__ Cv,
    int N, int K, int nmg) {
  __shared__ __bf16 lds[8][8192];              // [c*4 + ab*2 + kh][256*32]
  const int t = threadIdx.x, l = t & 63, w = t >> 6;
  const int nwg = gridDim.x, orig = blockIdx.x;
  const int q = nwg >> 3, r = nwg & 7, xcd = orig & 7, pos = orig >> 3;
  const int wgid = (xcd < r ? xcd*(q+1) : r*(q+1) + (xcd-r)*q) + pos;
  const int mgrp = wgid % nmg, n0 = (wgid / nmg) * 256;
  const int wm = w >> 2, wn = w & 3;
  const int fr = l & 15, c8 = l >> 4;
  const int swz = (c8 ^ ((fr >> 1) & 3)) * 8;
  const int roA = (wm*128 + fr) * 32 + swz;
  const int roB = (wn*64  + fr) * 32 + swz;
  const int col8 = ((t & 3) ^ ((t >> 3) & 3)) * 8;
  const int srow = t >> 2;
  const int sdst = (t >> 6) * 512;

  const __bf16* Wb = W + (size_t)n0 * K;
  const int ng = NMT * 16;

  float bv[4];
#pragma unroll
  for (int j = 0; j < 4; ++j) bv[j] = BIAS ? bias[n0 + wn*64 + fr + j*16] : 0.0f;

  f32x4 acc[8][4] = {};

#define ABASE(g2) (A + (size_t)(mgrp*NMT + ((g2) >> 4)) * 256 * K)
#define KOFS(g2)  (((g2) & 15) * 64)

  stage_half8(ABASE(0), &lds[0][0], K, 0,  col8, srow, sdst);
  stage_half8(Wb,       &lds[2][0], K, 0,  col8, srow, sdst);
  stage_half8(ABASE(0), &lds[1][0], K, 32, col8, srow, sdst);
  stage_half8(Wb,       &lds[3][0], K, 32, col8, srow, sdst);
  stage_half8(ABASE(1), &lds[4][0], K, 64, col8, srow, sdst);
  stage_half8(Wb,       &lds[6][0], K, 64, col8, srow, sdst);
  asm volatile("s_waitcnt vmcnt(4)" ::: "memory");
  __builtin_amdgcn_s_barrier();

  for (int g = 0; g < ng; ++g) {
    const int c = g & 1;
    const int rA = c*4, rB = c*4 + 2;
    bf16x8 afr0[4], afr1[4], bfr[4];
    // ---- P1: kh0 — read B, A-lo, A-hi (hi completes under MFMA) ----
#pragma unroll
    for (int j = 0; j < 4; ++j) bfr[j]  = *(const bf16x8*)&lds[rB][roB + j*512];
#pragma unroll
    for (int i = 0; i < 4; ++i) afr0[i] = *(const bf16x8*)&lds[rA][roA + i*512];
#pragma unroll
    for (int i = 0; i < 4; ++i) afr1[i] = *(const bf16x8*)&lds[rA][roA + (i+4)*512];
    if (g + 1 < ng)
      stage_half8(ABASE(g+1), &lds[(c^1)*4 + 1][0], K, KOFS(g+1) + 32, col8, srow, sdst);
    __builtin_amdgcn_s_barrier();
    __builtin_amdgcn_s_setprio(1);
#pragma unroll
    for (int i = 0; i < 4; ++i)
#pragma unroll
      for (int j = 0; j < 4; ++j)
        acc[i][j] = __builtin_amdgcn_mfma_f32_16x16x32_bf16(afr0[i], bfr[j], acc[i][j], 0, 0, 0);
    __builtin_amdgcn_s_setprio(0);
    __builtin_amdgcn_s_barrier();
    // ---- P2: kh0 hi — pure MFMA ----
    if (g + 1 < ng)
      stage_half8(Wb, &lds[(c^1)*4 + 3][0], K, KOFS(g+1) + 32, col8, srow, sdst);
    __builtin_amdgcn_s_barrier();
    __builtin_amdgcn_s_setprio(1);
#pragma unroll
    for (int i = 0; i < 4; ++i)
#pragma unroll
      for (int j = 0; j < 4; ++j)
        acc[i+4][j] = __builtin_amdgcn_mfma_f32_16x16x32_bf16(afr1[i], bfr[j], acc[i+4][j], 0, 0, 0);
    __builtin_amdgcn_s_setprio(0);
    if (g < ng - 1) { asm volatile("s_waitcnt vmcnt(8)" ::: "memory"); }
    else            { asm volatile("s_waitcnt vmcnt(0)" ::: "memory"); }
    __builtin_amdgcn_s_barrier();
    // ---- P3: kh1 — read B, A-lo, A-hi ----
#pragma unroll
    for (int j = 0; j < 4; ++j) bfr[j]  = *(const bf16x8*)&lds[rB + 1][roB + j*512];
#pragma unroll
    for (int i = 0; i < 4; ++i) afr0[i] = *(const bf16x8*)&lds[rA + 1][roA + i*512];
#pragma unroll
    for (int i = 0; i < 4; ++i) afr1[i] = *(const bf16x8*)&lds[rA + 1][roA + (i+4)*512];
    if (g + 2 < ng)
      stage_half8(ABASE(g+2), &lds[c*4][0], K, KOFS(g+2), col8, srow, sdst);
    __builtin_amdgcn_s_barrier();
    __builtin_amdgcn_s_setprio(1);
#pragma unroll
    for (int i = 0; i < 4; ++i)
#pragma unroll
      for (int j = 0; j < 4; ++j)
        acc[i][j] = __builtin_amdgcn_mfma_f32_16x16x32_bf16(afr0[i], bfr[j], acc[i][j], 0, 0, 0);
    __builtin_amdgcn_s_setprio(0);
    __builtin_amdgcn_s_barrier();
    // ---- P4: kh1 hi — pure MFMA ----
    if (g + 2 < ng)
      stage_half8(Wb, &lds[c*4 + 2][0], K, KOFS(g+2), col8, srow, sdst);
    __builtin_amdgcn_s_barrier();
    __builtin_amdgcn_s_setprio(1);
#pragma unroll
    for (int i = 0; i < 4; ++i)
#pragma unroll
      for (int j = 0; j < 4; ++j)
        acc[i+4][j] = __builtin_amdgcn_mfma_f32_16x16x32_bf16(afr1[i], bfr[j], acc[i+4][j], 0, 0, 0);
    __builtin_amdgcn_s_setprio(0);
    if (g < ng - 2)       { asm volatile("s_waitcnt vmcnt(8)" ::: "memory"); }
    else if (g == ng - 2) { asm volatile("s_waitcnt vmcnt(4)" ::: "memory"); }
    __builtin_amdgcn_s_barrier();
    // ---- per-tile epilogue (regs only) ----
    if ((g & 15) == 15) {
      const int orow = (mgrp*NMT + (g >> 4)) * 256 + wm*128 + c8 * 4;
      const int ocol = n0 + wn*64 + fr;
#pragma unroll
      for (int i = 0; i < 8; ++i)
#pragma unroll
        for (int j = 0; j < 4; ++j) {
#pragma unroll
          for (int rr = 0; rr < 4; ++rr) {
            float v = acc[i][j][rr] + bv[j];
            if (RELU) v = fmaxf(v, 0.0f);
            if (OUTBF16)
              ((__bf16*)Cv)[(size_t)(orow + i*16 + rr) * N + ocol + j*16] = (__bf16)v;
            else
              ((float*)Cv)[(size_t)(orow + i*16 + rr) * N + ocol + j*16] = v;
          }
          acc[i][j] = (f32x4){};
        }
    }
  }
#undef ABASE
#undef KOFS
}

// ---------------------------------------------------------------------------
// Deep-prefetch 128x128 GEMM (r6-verified; wo/down shapes).
// ---------------------------------------------------------------------------
template<int T, int BM>
__device__ inline void stage2(const __bf16* __restrict__ Ab,
                              const __bf16* __restrict__ Wb,
                              __bf16* la, __bf16* lb, int K, int k0, int t) {
  const int col8 = (t & 3) ^ ((t >> 3) & 3);
  const int cofs = k0 + col8 * 8;
  const int wbase = (t >> 6) * 512;
#pragma unroll
  for (int p = 0; p < (BM * 32) / (T * 8); ++p) {
    const int row = p * (T >> 2) + (t >> 2);
    gload16(Ab + (size_t)row * K + cofs, la + p * T * 8 + wbase);
    gload16(Wb + (size_t)row * K + cofs, lb + p * T * 8 + wbase);
  }
}

template<int RW, int WM, int WN, bool BIAS, bool RELU, bool OUTBF16>
__global__ __launch_bounds__(WM*WN*64, 2) void gemm_deep(
    const __bf16* __restrict__ A, const __bf16* __restrict__ W,
    const float* __restrict__ bias, void* __restrict__ Cv,
    int N, int K, int nbx) {
  constexpr int T  = WM * WN * 64;
  constexpr int BM = WM * RW * 16;
  __shared__ __bf16 lds[4][2][BM * 32];
  const int t = threadIdx.x, l = t & 63, w = t >> 6;
  const int nwg = gridDim.x, orig = blockIdx.x;
  const int q = nwg >> 3, r = nwg & 7, xcd = orig & 7, pos = orig >> 3;
  const int wgid = (xcd < r ? xcd*(q+1) : r*(q+1) + (xcd-r)*q) + pos;
  const int m0 = (wgid % nbx) * BM, n0 = (wgid / nbx) * BM;
  const int wm = w / WN, wn = w % WN;
  const int fr = l & 15, c8 = l >> 4;
  const int slot = (c8 ^ ((fr >> 1) & 3)) * 8;

  const __bf16* Abase = A + (size_t)m0 * K;
  const __bf16* Wbase = W + (size_t)n0 * K;

  f32x4 acc[RW][4] = {};

  const int nk = K >> 5;
  stage2<T,BM>(Abase, Wbase, &lds[0][0][0], &lds[0][1][0], K, 0,  t);
  stage2<T,BM>(Abase, Wbase, &lds[1][0][0], &lds[1][1][0], K, 32, t);
  stage2<T,BM>(Abase, Wbase, &lds[2][0][0], &lds[2][1][0], K, 64, t);

  for (int kt = 0; kt < nk; ++kt) {
    const int cur = kt & 3;
    if (kt + 3 < nk) {
      const int nb = (kt + 3) & 3;
      stage2<T,BM>(Abase, Wbase, &lds[nb][0][0], &lds[nb][1][0], K, (kt+3)*32, t);
      asm volatile("s_waitcnt vmcnt(8)" ::: "memory");
    } else if (kt + 2 < nk) {
      asm volatile("s_waitcnt vmcnt(8)" ::: "memory");
    } else if (kt + 1 < nk) {
      asm volatile("s_waitcnt vmcnt(4)" ::: "memory");
    } else {
      asm volatile("s_waitcnt vmcnt(0)" ::: "memory");
    }
    __builtin_amdgcn_s_barrier();
    __builtin_amdgcn_sched_barrier(0);
    const __bf16* La = &lds[cur][0][0];
    const __bf16* Lb = &lds[cur][1][0];
    bf16x8 bfr[4];
#pragma unroll
    for (int j = 0; j < 4; ++j)
      bfr[j] = *(const bf16x8*)&Lb[(wn*64 + j*16 + fr) * 32 + slot];
    __builtin_amdgcn_s_setprio(1);
#pragma unroll
    for (int i = 0; i < RW; ++i) {
      bf16x8 af = *(const bf16x8*)&La[(wm*(RW*16) + i*16 + fr) * 32 + slot];
#pragma unroll
      for (int j = 0; j < 4; ++j)
        acc[i][j] = __builtin_amdgcn_mfma_f32_16x16x32_bf16(af, bfr[j], acc[i][j], 0, 0, 0);
    }
    __builtin_amdgcn_s_setprio(0);
    __builtin_amdgcn_sched_barrier(0);
    __builtin_amdgcn_s_barrier();
    __builtin_amdgcn_sched_barrier(0);
  }

  const int orow = m0 + wm*(RW*16) + c8 * 4;
  const int ocol = n0 + wn*64 + fr;
#pragma unroll
  for (int i = 0; i < RW; ++i)
#pragma unroll
    for (int j = 0; j < 4; ++j) {
      const int col = ocol + j * 16;
      const float bv = BIAS ? bias[col] : 0.0f;
#pragma unroll
      for (int rr = 0; rr < 4; ++rr) {
        float v = acc[i][j][rr] + bv;
        if (RELU) v = fmaxf(v, 0.0f);
        if (OUTBF16)
          ((__bf16*)Cv)[(size_t)(orow + i*16 + rr) * N + col] = (__bf16)v;
        else
          ((float*)Cv)[(size_t)(orow + i*16 + rr) * N + col] = v;
      }
    }
}

// ---------------------------------------------------------------------------
// 128x128 2-phase GEMM (fallback unembed only: fp32 W reg-staged).
// ---------------------------------------------------------------------------
template<bool WBF16, bool BIAS, bool RELU, bool OUTBF16>
__global__ __launch_bounds__(256) void gemm_fast(
    const __bf16* __restrict__ A, const void* __restrict__ Wv,
    const float* __restrict__ bias, void* __restrict__ Cv, int N, int K) {
  __shared__ __bf16 As[128][32];
  __shared__ __bf16 Bs[128][32];
  const int t = threadIdx.x;
  const int m0 = blockIdx.x * 128, n0 = blockIdx.y * 128;
  const int l = t & 63, w = t >> 6;
  const int wm = (w >> 1) * 64, wn = (w & 1) * 64;
  const int fr = l & 15, fk = (l >> 4) * 8;
  const int crow = l >> 2, ccol = (l & 3) * 8;
  const int wrow = t >> 1, wcol = (t & 1) * 16;

  const __bf16* Wb = (const __bf16*)Wv;
  const float*  Wf = (const float*)Wv;

  f32x4 acc[4][4] = {};

  for (int k0 = 0; k0 < K; k0 += 32) {
    float4 wf0, wf1, wf2, wf3;
    if (!WBF16) {
      const float* wp = Wf + (size_t)(n0 + wrow) * K + k0 + wcol;
      wf0 = *(const float4*)(wp);
      wf1 = *(const float4*)(wp + 4);
      wf2 = *(const float4*)(wp + 8);
      wf3 = *(const float4*)(wp + 12);
    }
    __syncthreads();
#pragma unroll
    for (int i = 0; i < 2; ++i) {
      const int c = 2 * w + i;
      gload16(A + (size_t)(m0 + c*16 + crow) * K + k0 + ccol, (__bf16*)As + c*512);
      if (WBF16)
        gload16(Wb + (size_t)(n0 + c*16 + crow) * K + k0 + ccol, (__bf16*)Bs + c*512);
    }
    if (!WBF16) {
      *(bf16x8*)&Bs[wrow][wcol]     = to_bf8(wf0, wf1);
      *(bf16x8*)&Bs[wrow][wcol + 8] = to_bf8(wf2, wf3);
    }
    __syncthreads();
    bf16x8 af[4], bf[4];
#pragma unroll
    for (int i = 0; i < 4; ++i) af[i] = *(const bf16x8*)&As[wm + i*16 + fr][fk];
#pragma unroll
    for (int j = 0; j < 4; ++j) bf[j] = *(const bf16x8*)&Bs[wn + j*16 + fr][fk];
#pragma unroll
    for (int i = 0; i < 4; ++i)
#pragma unroll
      for (int j = 0; j < 4; ++j)
        acc[i][j] = __builtin_amdgcn_mfma_f32_16x16x32_bf16(af[i], bf[j], acc[i][j], 0, 0, 0);
  }

  const int orow = m0 + wm + (l >> 4) * 4;
  const int ocol = n0 + wn + fr;
#pragma unroll
  for (int i = 0; i < 4; ++i)
#pragma unroll
    for (int j = 0; j < 4; ++j) {
      const int col = ocol + j * 16;
      const float bv = BIAS ? bias[col] : 0.0f;
#pragma unroll
      for (int r = 0; r < 4; ++r) {
        float v = acc[i][j][r] + bv;
        if (RELU) v = fmaxf(v, 0.0f);
        if (OUTBF16)
          ((__bf16*)Cv)[(size_t)(orow + i*16 + r) * N + col] = (__bf16)v;
        else
          ((float*)Cv)[(size_t)(orow + i*16 + r) * N + col] = v;
      }
    }
}

// ---------------------------------------------------------------------------
// x = bf16(LN(y + x) * s + b) ; bf16 residual in/out (single buffer).
// ---------------------------------------------------------------------------
__global__ __launch_bounds__(256) void ln_res_kernel(
    const __bf16* __restrict__ y, __bf16* __restrict__ x,
    const float* __restrict__ sc, const float* __restrict__ bs) {
  __shared__ float red[8];
  int row = blockIdx.x, t = threadIdx.x;
  bf16x4 a4 = *(const bf16x4*)(y + (size_t)row * EE + t * 4);
  bf16x4 c4 = *(const bf16x4*)(x + (size_t)row * EE + t * 4);
  float v0 = (float)a4[0] + (float)c4[0], v1 = (float)a4[1] + (float)c4[1];
  float v2 = (float)a4[2] + (float)c4[2], v3 = (float)a4[3] + (float)c4[3];
  float s = v0 + v1 + v2 + v3;
  float q = v0*v0 + v1*v1 + v2*v2 + v3*v3;
#pragma unroll
  for (int off = 32; off; off >>= 1) {
    s += __shfl_xor(s, off);
    q += __shfl_xor(q, off);
  }
  int w = t >> 6;
  if ((t & 63) == 0) { red[w] = s; red[4 + w] = q; }
  __syncthreads();
  s = red[0] + red[1] + red[2] + red[3];
  q = red[4] + red[5] + red[6] + red[7];
  float mean = s * (1.0f / EE);
  float var  = q * (1.0f / EE) - mean * mean;
  float r = 1.0f / sqrtf(var + 1e-6f);
  float4 ss = ((const float4*)sc)[t];
  float4 bb = ((const float4*)bs)[t];
  bf16x4 ob4;
  ob4[0] = (__bf16)((v0 - mean) * r * ss.x + bb.x);
  ob4[1] = (__bf16)((v1 - mean) * r * ss.y + bb.y);
  ob4[2] = (__bf16)((v2 - mean) * r * ss.z + bb.z);
  ob4[3] = (__bf16)((v3 - mean) * r * ss.w + bb.w);
  *(bf16x4*)(x + (size_t)row * EE + t * 4) = ob4;
}

// ---------------------------------------------------------------------------
// MFMA flash attention (r8/r11-verified: 128-query tile, 4 waves, 256 thr,
// 1-D grid 512 with z-pairing).
// ---------------------------------------------------------------------------
__global__ __launch_bounds__(256) void attn_mfma(
    const __bf16* __restrict__ qkv, const int* __restrict__ ls,
    __bf16* __restrict__ out) {
  const int id = blockIdx.x;
  const int z = id >> 8, rem = id & 255;
  const int qt0 = rem & 15, h = rem >> 4, b = z;
  const int qt = z ? (15 - qt0) : qt0;
  __shared__ f32x4 lds4[2304];             // 36864 B
  char* lds = (char*)lds4;
  __bf16* Ks = (__bf16*)lds;               // [64][72]
  __bf16* Vs = (__bf16*)(lds + 9216);      // [64][72] transposed (d-major)
  __shared__ int redmin[4];
  const int t = threadIdx.x, w = t >> 6, l = t & 63;
  __bf16* Pq = (__bf16*)(lds + 18432 + w * 4608);  // [32][72] per wave
  const int r = l & 31, hi = l >> 5;
  const int qb = qt * 128, qw = qb + w * 32, qg = qw + r;
  const int Lq = ls[b*SS + qg];

  {
    int mn = Lq;
#pragma unroll
    for (int off = 1; off < 64; off <<= 1) mn = min(mn, __shfl_xor(mn, off));
    if (l == 0) redmin[w] = mn;
  }

  bf16x8 qf[4];
  {
    const __bf16* qrow = qkv + (size_t)(b*SS + qg) * 3*EE + EE + h*DD + 8*hi;
#pragma unroll
    for (int ds = 0; ds < 4; ++ds) qf[ds] = *(const bf16x8*)(qrow + 16*ds);
  }
  __syncthreads();
  const int ktmin = min(min(redmin[0], redmin[1]), min(redmin[2], redmin[3])) >> 6;
  const int ktmax = 2*qt + 1;

  f32x16 oacc[2] = {};
  float m_r = NEG_HUGE, lsum = 0.0f;

  for (int kt = ktmin; kt <= ktmax; ++kt) {
    __syncthreads();
    {
      const int kr = t >> 2, c0 = (t & 3) * 16;
      const __bf16* kg = qkv + (size_t)(b*SS + kt*64 + kr) * 3*EE + h*DD + c0;
      const __bf16* vg = kg + 2*EE;
      bf16x8 k0 = *(const bf16x8*)kg;
      bf16x8 k1 = *(const bf16x8*)(kg + 8);
      bf16x8 v0 = *(const bf16x8*)vg;
      bf16x8 v1 = *(const bf16x8*)(vg + 8);
      *(bf16x8*)&Ks[kr*72 + c0]     = k0;
      *(bf16x8*)&Ks[kr*72 + c0 + 8] = k1;
      const int vc = (kr + 8*(t & 3)) & 63;
#pragma unroll
      for (int j = 0; j < 8; ++j) {
        Vs[(c0 + j)*72 + vc]     = v0[j];
        Vs[(c0 + 8 + j)*72 + vc] = v1[j];
      }
    }
    __syncthreads();

    bool act0 = (kt*64)      <= (qw + 31);
    bool act1 = (kt*64 + 32) <= (qw + 31);
    if (!act0) continue;

    f32x16 st[2];
    st[0] = (f32x16){};
    st[1] = (f32x16){};
#pragma unroll
    for (int ds = 0; ds < 4; ++ds) {
      bf16x8 kf = *(const bf16x8*)&Ks[(r)*72 + 16*ds + 8*hi];
      st[0] = __builtin_amdgcn_mfma_f32_32x32x16_bf16(kf, qf[ds], st[0], 0, 0, 0);
    }
    if (act1) {
#pragma unroll
      for (int ds = 0; ds < 4; ++ds) {
        bf16x8 kf = *(const bf16x8*)&Ks[(32 + r)*72 + 16*ds + 8*hi];
        st[1] = __builtin_amdgcn_mfma_f32_32x32x16_bf16(kf, qf[ds], st[1], 0, 0, 0);
      }
    }

    float tmax = NEG_HUGE;
#pragma unroll
    for (int kt2 = 0; kt2 < 2; ++kt2) {
#pragma unroll
      for (int reg = 0; reg < 16; ++reg) {
        const int key = kt*64 + 32*kt2 + (reg & 3) + 8*(reg >> 2) + 4*hi;
        float s = (kt2 == 0 || act1) ? st[kt2][reg] * 0.125f : NEG_HUGE;
        const bool valid = (key >= Lq) && (key <= qg);
        s = valid ? s : NEG_HUGE;
        st[kt2][reg] = s;
        tmax = fmaxf(tmax, s);
      }
    }
    tmax = fmaxf(tmax, __shfl_xor(tmax, 32));
    const float m_new = fmaxf(m_r, tmax);
    const float alpha = __expf(m_r - m_new);
    m_r = m_new;

    float psum = 0.0f;
#pragma unroll
    for (int kt2 = 0; kt2 < 2; ++kt2) {
#pragma unroll
      for (int g2 = 0; g2 < 4; ++g2) {
        bf16x4 pk;
#pragma unroll
        for (int j = 0; j < 4; ++j) {
          float p = __expf(st[kt2][g2*4 + j] - m_new);
          psum += p;
          pk[j] = (__bf16)p;
        }
        *(bf16x4*)&Pq[r*72 + 32*kt2 + 8*g2 + 4*hi] = pk;
      }
    }
    psum += __shfl_xor(psum, 32);
    lsum = lsum * alpha + psum;
    oacc[0] *= alpha;
    oacc[1] *= alpha;

#pragma unroll
    for (int ks = 0; ks < 4; ++ks) {
      if (kt*64 + 16*ks > qw + 31) continue;
      bf16x8 pf = *(const bf16x8*)&Pq[r*72 + 16*ks + 8*hi];
#pragma unroll
      for (int mt = 0; mt < 2; ++mt) {
        const int d = 32*mt + r;
        const int vcol = (16*ks + 8*hi + 8*((d >> 4) & 3)) & 63;
        bf16x8 vf = *(const bf16x8*)&Vs[d*72 + vcol];
        oacc[mt] = __builtin_amdgcn_mfma_f32_32x32x16_bf16(vf, pf, oacc[mt], 0, 0, 0);
      }
    }
  }

  __syncthreads();
  float* Ot = (float*)(lds + w * 8448);        // [64][33] f32 per wave
  const float rinv = 1.0f / lsum;
#pragma unroll
  for (int mt = 0; mt < 2; ++mt)
#pragma unroll
    for (int reg = 0; reg < 16; ++reg) {
      const int d = 32*mt + (reg & 3) + 8*(reg >> 2) + 4*hi;
      Ot[d*33 + r] = oacc[mt][reg] * rinv;
    }
  __syncthreads();
  const int qr0 = l >> 4, dc = (l & 15) * 4;
#pragma unroll
  for (int it = 0; it < 8; ++it) {
    const int qr = qr0 + 4*it;
    bf16x4 ov;
    ov[0] = (__bf16)Ot[(dc+0)*33 + qr];
    ov[1] = (__bf16)Ot[(dc+1)*33 + qr];
    ov[2] = (__bf16)Ot[(dc+2)*33 + qr];
    ov[3] = (__bf16)Ot[(dc+3)*33 + qr];
    *(bf16x4*)(out + (size_t)(b*SS + qw + qr) * EE + h*DD + dc) = ov;
  }
}

// ---------------------------------------------------------------------------
extern "C" void kernel_launch(void* const* d_in, const int* in_sizes, int n_in,
                              void* d_out, int out_size, void* d_ws, size_t ws_size,
                              hipStream_t stream) {
  const int*   tokens     = (const int*)  d_in[0];
  const float* word_embed = (const float*)d_in[1];
  const float* pos_embed  = (const float*)d_in[2];
  const float* unembed_b  = (const float*)d_in[3];
  const float* kqv_w      = (const float*)d_in[4];
  const float* wo_w       = (const float*)d_in[5];
  const float* up_w       = (const float*)d_in[6];
  const float* up_b       = (const float*)d_in[7];
  const float* down_w     = (const float*)d_in[8];
  const float* down_b     = (const float*)d_in[9];
  const float* ln1_s      = (const float*)d_in[10];
  const float* ln1_b      = (const float*)d_in[11];
  const float* ln2_s      = (const float*)d_in[12];
  const float* ln2_b      = (const float*)d_in[13];
  float* logits = (float*)d_out;

  // d_out (524 MB) scratch map (all dead before the final GEMM writes logits):
  char* ob = (char*)d_out;
  __bf16* qkv  = (__bf16*)ob;                          // 24 MB
  __bf16* t0   = (__bf16*)(ob +  24ull*1024*1024);     //  8 MB
  __bf16* hbuf = (__bf16*)(ob +  32ull*1024*1024);     // 32 MB
  __bf16* ybuf = (__bf16*)(ob +  64ull*1024*1024);     //  8 MB (bf16)
  __bf16* wcvt = (__bf16*)(ob +  80ull*1024*1024);     // 50.4 MB bf16 weights
  __bf16* kqvb  = wcvt;
  __bf16* wob   = kqvb + (size_t)LL*3*EE*EE;
  __bf16* upb   = wob  + (size_t)LL*EE*EE;
  __bf16* downb = upb  + (size_t)LL*FF*EE;
  // ws: only what must survive the final GEMM (which overwrites all of d_out).
  int*    ls   = (int*)d_ws;                            // 64 KB
  __bf16* xb   = (__bf16*)((char*)d_ws + 65536);        // 8 MB (bf16 residual)
  __bf16* webf = (__bf16*)((char*)d_ws + 65536 + 8ull*1024*1024);
  const bool bigws = ws_size >= (size_t)(65536 + 8ull*1024*1024 + (size_t)VV*EE*2);

  lastart_scan<<<BB, 1024, 0, stream>>>(tokens, ls);
  embed_kernel<<<BS, 256, 0, stream>>>(tokens, ls, word_embed, pos_embed, xb);

  // weight pre-conversion (fp32 -> bf16)
  cvt_bf16_kernel<<<LL*3*EE*EE/2048, 256, 0, stream>>>(kqv_w,  kqvb,  LL*3*EE*EE);
  cvt_bf16_kernel<<<LL*EE*EE/2048,   256, 0, stream>>>(wo_w,   wob,   LL*EE*EE);
  cvt_bf16_kernel<<<LL*FF*EE/2048,   256, 0, stream>>>(up_w,   upb,   LL*FF*EE);
  cvt_bf16_kernel<<<LL*EE*FF/2048,   256, 0, stream>>>(down_w, downb, LL*EE*FF);
  if (bigws)
    cvt_bf16_kernel<<<VV*EE/2048, 256, 0, stream>>>(word_embed, webf, VV*EE);

  for (int l = 0; l < LL; ++l) {
    gemm_8ph<1,false,false,true><<<(BS/256)*(3*EE/256), 512, 0, stream>>>(
        xb, kqvb + (size_t)l*3*EE*EE, nullptr, qkv, 3*EE, EE, BS/256);
    attn_mfma<<<512, 256, 0, stream>>>(qkv, ls, t0);
    gemm_deep<4,2,2,false,false,true><<<(BS/128)*(EE/128), 256, 0, stream>>>(
        t0, wob + (size_t)l*EE*EE, nullptr, ybuf, EE, EE, BS/128);
    ln_res_kernel<<<BS, 256, 0, stream>>>(ybuf, xb, ln1_s + l*EE, ln1_b + l*EE);
    gemm_8ph<1,true,true,true><<<(BS/256)*(FF/256), 512, 0, stream>>>(
        xb, upb + (size_t)l*FF*EE, up_b + (size_t)l*FF, hbuf, FF, EE, BS/256);
    gemm_deep<4,2,2,true,false,true><<<(BS/128)*(EE/128), 256, 0, stream>>>(
        hbuf, downb + (size_t)l*EE*FF, down_b + (size_t)l*EE, ybuf, EE, FF, BS/128);
    ln_res_kernel<<<BS, 256, 0, stream>>>(ybuf, xb, ln2_s + l*EE, ln2_b + l*EE);
  }

  if (bigws) {
    gemm_8ph<8,true,false,false><<<(VV/256)*2, 512, 0, stream>>>(
        xb, webf, unembed_b, logits, VV, EE, 2);
  } else {
    gemm_fast<false,true,false,false><<<dim3(BS/128, VV/128), 256, 0, stream>>>(
        xb, word_embed, unembed_b, logits, VV, EE);
  }
}